// Round 1
// baseline (2278.058 us; speedup 1.0000x reference)
//
#include <hip/hip_runtime.h>
#include <math.h>

#define DIMD    1024
#define MLPD    4096
#define DSTATE  16
#define DCONV   4
#define HALF    1024
#define DINNER  2048
#define DTRANK  64
#define BSZ     2
#define SEQ     2048
#define NTOK    (BSZ*SEQ)   // 4096

typedef short bf16x8 __attribute__((ext_vector_type(8)));
typedef float f32x4  __attribute__((ext_vector_type(4)));
typedef unsigned short u16;

__device__ __forceinline__ u16 f2bf(float x) {
    union { float f; unsigned int u; } v; v.f = x;
    unsigned int r = (v.u + 0x7FFFu + ((v.u >> 16) & 1u)) >> 16;
    return (u16)r;
}

// ---------------- f32 -> bf16 convert ----------------
__global__ __launch_bounds__(256) void cvt_bf16_kernel(
        const float* __restrict__ in, u16* __restrict__ out, int n) {
    int i = blockIdx.x * 256 + threadIdx.x;
    if (i < n) out[i] = f2bf(in[i]);
}

// ---------------- LayerNorm (row of 1024) -> bf16 ----------------
__global__ __launch_bounds__(256) void ln_bf16_kernel(
        const float* __restrict__ x, const float* __restrict__ g,
        const float* __restrict__ b, u16* __restrict__ out) {
    __shared__ float sm[4];
    int row = blockIdx.x;
    int t = threadIdx.x;          // 0..255, each owns 4 floats
    const float4* xr = (const float4*)(x + (size_t)row * DIMD);
    float4 v = xr[t];
    float s = v.x + v.y + v.z + v.w;
    for (int off = 32; off > 0; off >>= 1) s += __shfl_down(s, off, 64);
    if ((t & 63) == 0) sm[t >> 6] = s;
    __syncthreads();
    float mu = (sm[0] + sm[1] + sm[2] + sm[3]) * (1.0f / DIMD);
    float dx = v.x - mu, dy = v.y - mu, dz = v.z - mu, dw = v.w - mu;
    float ss = dx*dx + dy*dy + dz*dz + dw*dw;
    for (int off = 32; off > 0; off >>= 1) ss += __shfl_down(ss, off, 64);
    __syncthreads();
    if ((t & 63) == 0) sm[t >> 6] = ss;
    __syncthreads();
    float var = (sm[0] + sm[1] + sm[2] + sm[3]) * (1.0f / DIMD);
    float rs = rsqrtf(var + 1e-5f);
    float4 gv = ((const float4*)g)[t];
    float4 bv = ((const float4*)b)[t];
    u16* o = out + (size_t)row * DIMD + t * 4;
    o[0] = f2bf(dx * rs * gv.x + bv.x);
    o[1] = f2bf(dy * rs * gv.y + bv.y);
    o[2] = f2bf(dz * rs * gv.z + bv.z);
    o[3] = f2bf(dw * rs * gv.w + bv.w);
}

// ---------------- GEMM: C[M,N] = A[M,K] * W[N,K]^T (bf16 in, f32 acc) ----
// EPI: 0 = plain f32 store
//      1 = bias + softplus, f32 store
//      2 = bias + exact gelu, bf16 store
//      3 = residual add, f32 store
//      4 = bias + residual add, f32 store
// Fragment layouts (m89/m91-verified, guide §3):
//   A/B operand: row(A)/row(W) = lane&15, k = (lane>>4)*8 + j
//   C/D:         col = lane&15, row = (lane>>4)*4 + reg
template<int EPI>
__global__ __launch_bounds__(64) void gemm_mfma_kernel(
        const u16* __restrict__ A, int lda,
        const u16* __restrict__ W, int K, int N,
        const float* __restrict__ bias, const float* __restrict__ resid,
        float* __restrict__ Cf, u16* __restrict__ Cb) {
    int m0 = blockIdx.x * 16;
    int n0 = blockIdx.y * 16;
    int lane = threadIdx.x;
    int r = lane & 15, quad = lane >> 4;
    f32x4 acc = {0.f, 0.f, 0.f, 0.f};
    const u16* ap = A + (size_t)(m0 + r) * lda + quad * 8;
    const u16* wp = W + (size_t)(n0 + r) * K   + quad * 8;
    for (int k = 0; k < K; k += 32) {
        bf16x8 av = *(const bf16x8*)(ap + k);
        bf16x8 bv = *(const bf16x8*)(wp + k);
        acc = __builtin_amdgcn_mfma_f32_16x16x32_bf16(av, bv, acc, 0, 0, 0);
    }
    int col = n0 + r;
    #pragma unroll
    for (int i = 0; i < 4; ++i) {
        int row = m0 + quad * 4 + i;
        size_t idx = (size_t)row * N + col;
        float v = acc[i];
        if (EPI == 1) { v += bias[col]; v = (v > 20.f) ? v : log1pf(expf(v)); }
        if (EPI == 2) { v += bias[col]; v = 0.5f * v * (1.0f + erff(v * 0.70710678118654752f)); }
        if (EPI == 3) { v += resid[idx]; }
        if (EPI == 4) { v += bias[col] + resid[idx]; }
        if (EPI == 2) Cb[idx] = f2bf(v);
        else          Cf[idx] = v;
    }
}

// ---------------- depthwise conv(K=4, pad left=1,right=2) + SiLU ----------
// xz: [B*L, 2048] f32 (x half = cols 0..1023, z half = cols 1024..2047)
// writes u_f (f32), u_bf (bf16), and z-part of ycat (bf16, cols 1024..2047)
__global__ __launch_bounds__(256) void conv_silu_kernel(
        const float* __restrict__ xz,
        const float* __restrict__ wx, const float* __restrict__ bx,
        const float* __restrict__ wz, const float* __restrict__ bz,
        float* __restrict__ u_f, u16* __restrict__ u_bf,
        u16* __restrict__ ycat) {
    int c  = blockIdx.x * 256 + threadIdx.x;   // 0..1023
    int bl = blockIdx.y;                       // 0..B*L-1
    int l  = bl & (SEQ - 1);
    float accx = bx[c], accz = bz[c];
    #pragma unroll
    for (int k = 0; k < DCONV; ++k) {
        int lp = l + k - 1;
        if (lp >= 0 && lp < SEQ) {
            const float* rowp = xz + (size_t)(bl + (lp - l)) * DINNER;
            accx += rowp[c]        * wx[c * DCONV + k];
            accz += rowp[HALF + c] * wz[c * DCONV + k];
        }
    }
    float sx = accx / (1.f + expf(-accx));
    float sz = accz / (1.f + expf(-accz));
    size_t o = (size_t)bl * HALF + c;
    u_f[o]  = sx;
    u_bf[o] = f2bf(sx);
    ycat[(size_t)bl * DINNER + HALF + c] = f2bf(sz);
}

// ---------------- selective scan ----------------
// thread = (b, d, n); 16 lanes per (b,d) chain; butterfly-reduce h*C over n.
// writes y + u*Dp as bf16 into the first half of ycat.
__global__ __launch_bounds__(256) void scan_kernel(
        const float* __restrict__ delta,  // [B*L, HALF]
        const float* __restrict__ u_f,    // [B*L, HALF]
        const float* __restrict__ x_dbl,  // [B*L, 96]; B at 64..79, C at 80..95
        const float* __restrict__ A_log,  // [HALF, 16]
        const float* __restrict__ Dp,     // [HALF]
        u16* __restrict__ ycat) {
    int t   = blockIdx.x * 256 + threadIdx.x;
    int n   = t & 15;
    int cid = t >> 4;            // 0..2047
    int d   = cid & (HALF - 1);
    int b   = cid >> 10;
    float Ac = -expf(A_log[d * DSTATE + n]);
    float Dv = Dp[d];
    float h = 0.f;
    size_t base_du = (size_t)b * SEQ * HALF + d;
    size_t base_x  = (size_t)b * SEQ * 96;
    // prefetch l=0
    float dl = delta[base_du];
    float uv = u_f[base_du];
    float Bv = x_dbl[base_x + 64 + n];
    float Cv = x_dbl[base_x + 80 + n];
    for (int l = 0; l < SEQ; ++l) {
        float dln = 0.f, uvn = 0.f, Bvn = 0.f, Cvn = 0.f;
        if (l + 1 < SEQ) {
            size_t o = base_du + (size_t)(l + 1) * HALF;
            dln = delta[o]; uvn = u_f[o];
            size_t ox = base_x + (size_t)(l + 1) * 96;
            Bvn = x_dbl[ox + 64 + n]; Cvn = x_dbl[ox + 80 + n];
        }
        h = expf(dl * Ac) * h + dl * Bv * uv;
        float contrib = h * Cv;
        contrib += __shfl_xor(contrib, 8, 64);
        contrib += __shfl_xor(contrib, 4, 64);
        contrib += __shfl_xor(contrib, 2, 64);
        contrib += __shfl_xor(contrib, 1, 64);
        if (n == 0) {
            ycat[((size_t)(b * SEQ + l)) * DINNER + d] = f2bf(contrib + uv * Dv);
        }
        dl = dln; uv = uvn; Bv = Bvn; Cv = Cvn;
    }
}

// ---------------- host-side orchestration ----------------
extern "C" void kernel_launch(void* const* d_in, const int* in_sizes, int n_in,
                              void* d_out, int out_size, void* d_ws, size_t ws_size,
                              hipStream_t stream) {
    const float* x         = (const float*)d_in[0];
    const float* ln1_g     = (const float*)d_in[1];
    const float* ln1_b     = (const float*)d_in[2];
    const float* in_proj_w = (const float*)d_in[3];
    const float* conv_x_w  = (const float*)d_in[4];
    const float* conv_x_b  = (const float*)d_in[5];
    const float* conv_z_w  = (const float*)d_in[6];
    const float* conv_z_b  = (const float*)d_in[7];
    const float* x_proj_w  = (const float*)d_in[8];
    const float* dt_proj_w = (const float*)d_in[9];
    const float* dt_proj_b = (const float*)d_in[10];
    const float* A_log     = (const float*)d_in[11];
    const float* Dp        = (const float*)d_in[12];
    const float* out_proj_w= (const float*)d_in[13];
    const float* ln2_g     = (const float*)d_in[14];
    const float* ln2_b     = (const float*)d_in[15];
    const float* mlp_w1    = (const float*)d_in[16];
    const float* mlp_b1    = (const float*)d_in[17];
    const float* mlp_w2    = (const float*)d_in[18];
    const float* mlp_b2    = (const float*)d_in[19];
    float* out = (float*)d_out;

    char* p = (char*)d_ws;
    auto alloc = [&](size_t bytes) {
        char* r = p; p += (bytes + 255) & ~(size_t)255; return r;
    };
    u16*   w_in   = (u16*)  alloc((size_t)DINNER * DIMD * 2);
    u16*   w_xp   = (u16*)  alloc((size_t)96 * HALF * 2);
    u16*   w_dt   = (u16*)  alloc((size_t)HALF * DTRANK * 2);
    u16*   w_out  = (u16*)  alloc((size_t)DIMD * DINNER * 2);
    u16*   w_m1   = (u16*)  alloc((size_t)MLPD * DIMD * 2);
    u16*   w_m2   = (u16*)  alloc((size_t)DIMD * MLPD * 2);
    u16*   xn_bf  = (u16*)  alloc((size_t)NTOK * DIMD * 2);
    float* xz     = (float*)alloc((size_t)NTOK * DINNER * 4);
    float* u_f    = (float*)alloc((size_t)NTOK * HALF * 4);
    u16*   u_bf   = (u16*)  alloc((size_t)NTOK * HALF * 2);
    u16*   ycat   = (u16*)  alloc((size_t)NTOK * DINNER * 2);
    float* x_dbl  = (float*)alloc((size_t)NTOK * 96 * 4);
    u16*   xdbl_bf= (u16*)  alloc((size_t)NTOK * 96 * 2);
    float* delta  = (float*)alloc((size_t)NTOK * HALF * 4);
    float* x2     = (float*)alloc((size_t)NTOK * DIMD * 4);
    u16*   ln2_bf = (u16*)  alloc((size_t)NTOK * DIMD * 2);
    u16*   mlp_h  = (u16*)xz;  // alias: xz dead after conv, mlp_h needed later (same 32MB)

    auto cvt = [&](const float* src, u16* dst, int n) {
        cvt_bf16_kernel<<<(n + 255) / 256, 256, 0, stream>>>(src, dst, n);
    };
    // weight conversions
    cvt(in_proj_w,  w_in,  DINNER * DIMD);
    cvt(x_proj_w,   w_xp,  96 * HALF);
    cvt(dt_proj_w,  w_dt,  HALF * DTRANK);
    cvt(out_proj_w, w_out, DIMD * DINNER);
    cvt(mlp_w1,     w_m1,  MLPD * DIMD);
    cvt(mlp_w2,     w_m2,  DIMD * MLPD);

    // LN1
    ln_bf16_kernel<<<NTOK, 256, 0, stream>>>(x, ln1_g, ln1_b, xn_bf);

    // in_proj: [4096,2048] = xn[4096,1024] @ W[2048,1024]^T
    gemm_mfma_kernel<0><<<dim3(NTOK/16, DINNER/16), 64, 0, stream>>>(
        xn_bf, DIMD, w_in, DIMD, DINNER, nullptr, nullptr, xz, nullptr);

    // depthwise conv + silu (x and z halves)
    conv_silu_kernel<<<dim3(HALF/256, NTOK), 256, 0, stream>>>(
        xz, conv_x_w, conv_x_b, conv_z_w, conv_z_b, u_f, u_bf, ycat);

    // x_proj: [4096,96] = u[4096,1024] @ W[96,1024]^T
    gemm_mfma_kernel<0><<<dim3(NTOK/16, 96/16), 64, 0, stream>>>(
        u_bf, HALF, w_xp, HALF, 96, nullptr, nullptr, x_dbl, nullptr);

    // convert x_dbl to bf16 (dt columns feed dt_proj)
    cvt(x_dbl, xdbl_bf, NTOK * 96);

    // dt_proj: delta[4096,1024] = softplus(dt[4096,64] @ W[1024,64]^T + b)
    gemm_mfma_kernel<1><<<dim3(NTOK/16, HALF/16), 64, 0, stream>>>(
        xdbl_bf, 96, w_dt, DTRANK, HALF, dt_proj_b, nullptr, delta, nullptr);

    // selective scan -> y half of ycat
    scan_kernel<<<(BSZ * HALF * DSTATE) / 256, 256, 0, stream>>>(
        delta, u_f, x_dbl, A_log, Dp, ycat);

    // out_proj + residual: x2 = x + ycat[4096,2048] @ W[1024,2048]^T
    gemm_mfma_kernel<3><<<dim3(NTOK/16, DIMD/16), 64, 0, stream>>>(
        ycat, DINNER, w_out, DINNER, DIMD, nullptr, x, x2, nullptr);

    // LN2
    ln_bf16_kernel<<<NTOK, 256, 0, stream>>>(x2, ln2_g, ln2_b, ln2_bf);

    // MLP1: mlp_h[4096,4096] = gelu(ln2 @ W1^T + b1)  (bf16 out)
    gemm_mfma_kernel<2><<<dim3(NTOK/16, MLPD/16), 64, 0, stream>>>(
        ln2_bf, DIMD, w_m1, DIMD, MLPD, mlp_b1, nullptr, nullptr, mlp_h);

    // MLP2 + residual: out = x2 + mlp_h @ W2^T + b2
    gemm_mfma_kernel<4><<<dim3(NTOK/16, DIMD/16), 64, 0, stream>>>(
        mlp_h, MLPD, w_m2, MLPD, DIMD, mlp_b2, x2, out, nullptr);
}

// Round 2
// 571.583 us; speedup vs baseline: 3.9855x; 3.9855x over previous
//
#include <hip/hip_runtime.h>
#include <math.h>

#define DIMD    1024
#define MLPD    4096
#define DSTATE  16
#define DCONV   4
#define HALF    1024
#define DINNER  2048
#define DTRANK  64
#define BSZ     2
#define SEQ     2048
#define NTOK    (BSZ*SEQ)   // 4096
#define NCH     32
#define CL      (SEQ/NCH)   // 64

typedef short bf16x8 __attribute__((ext_vector_type(8)));
typedef float f32x4  __attribute__((ext_vector_type(4)));
typedef unsigned short u16;
typedef unsigned int   u32;

__device__ __forceinline__ u16 f2bf(float x) {
    union { float f; unsigned int u; } v; v.f = x;
    unsigned int r = (v.u + 0x7FFFu + ((v.u >> 16) & 1u)) >> 16;
    return (u16)r;
}

// ---------------- f32 -> bf16 convert ----------------
__global__ __launch_bounds__(256) void cvt_bf16_kernel(
        const float* __restrict__ in, u16* __restrict__ out, int n) {
    int i = blockIdx.x * 256 + threadIdx.x;
    if (i < n) out[i] = f2bf(in[i]);
}

// ---------------- LayerNorm (row of 1024) -> bf16 ----------------
__global__ __launch_bounds__(256) void ln_bf16_kernel(
        const float* __restrict__ x, const float* __restrict__ g,
        const float* __restrict__ b, u16* __restrict__ out) {
    __shared__ float sm[4];
    int row = blockIdx.x;
    int t = threadIdx.x;          // 0..255, each owns 4 floats
    const float4* xr = (const float4*)(x + (size_t)row * DIMD);
    float4 v = xr[t];
    float s = v.x + v.y + v.z + v.w;
    for (int off = 32; off > 0; off >>= 1) s += __shfl_down(s, off, 64);
    if ((t & 63) == 0) sm[t >> 6] = s;
    __syncthreads();
    float mu = (sm[0] + sm[1] + sm[2] + sm[3]) * (1.0f / DIMD);
    float dx = v.x - mu, dy = v.y - mu, dz = v.z - mu, dw = v.w - mu;
    float ss = dx*dx + dy*dy + dz*dz + dw*dw;
    for (int off = 32; off > 0; off >>= 1) ss += __shfl_down(ss, off, 64);
    __syncthreads();
    if ((t & 63) == 0) sm[t >> 6] = ss;
    __syncthreads();
    float var = (sm[0] + sm[1] + sm[2] + sm[3]) * (1.0f / DIMD);
    float rs = rsqrtf(var + 1e-5f);
    float4 gv = ((const float4*)g)[t];
    float4 bv = ((const float4*)b)[t];
    u16* o = out + (size_t)row * DIMD + t * 4;
    o[0] = f2bf(dx * rs * gv.x + bv.x);
    o[1] = f2bf(dy * rs * gv.y + bv.y);
    o[2] = f2bf(dz * rs * gv.z + bv.z);
    o[3] = f2bf(dw * rs * gv.w + bv.w);
}

// ---------------- small GEMM (one wave, 16x16 tile) ----------------
// C[M,N] = A[M,K] * W[N,K]^T.  EPI: 0 plain f32, 1 bias+softplus f32.
template<int EPI>
__global__ __launch_bounds__(64) void gemm_mfma_kernel(
        const u16* __restrict__ A, int lda,
        const u16* __restrict__ W, int K, int N,
        const float* __restrict__ bias,
        float* __restrict__ Cf) {
    int m0 = blockIdx.x * 16;
    int n0 = blockIdx.y * 16;
    int lane = threadIdx.x;
    int r = lane & 15, quad = lane >> 4;
    f32x4 acc = {0.f, 0.f, 0.f, 0.f};
    const u16* ap = A + (size_t)(m0 + r) * lda + quad * 8;
    const u16* wp = W + (size_t)(n0 + r) * K   + quad * 8;
    for (int k = 0; k < K; k += 32) {
        bf16x8 av = *(const bf16x8*)(ap + k);
        bf16x8 bv = *(const bf16x8*)(wp + k);
        acc = __builtin_amdgcn_mfma_f32_16x16x32_bf16(av, bv, acc, 0, 0, 0);
    }
    int col = n0 + r;
    #pragma unroll
    for (int i = 0; i < 4; ++i) {
        int row = m0 + quad * 4 + i;
        size_t idx = (size_t)row * N + col;
        float v = acc[i];
        if (EPI == 1) { v += bias[col]; v = (v > 20.f) ? v : log1pf(expf(v)); }
        Cf[idx] = v;
    }
}

// ---------------- big GEMM: 128x128 tile, 4 waves, global_load_lds --------
// C[M,N] = A[M,K] * W[N,K]^T, bf16 in, f32 acc. M,N %128==0, K %64==0.
// EPI: 0 plain f32 | 2 bias+gelu bf16 | 3 +resid f32 | 4 bias+resid f32
template<int EPI>
__global__ __launch_bounds__(256) void gemm128_kernel(
        const u16* __restrict__ A, const u16* __restrict__ W,
        int K, int N,
        const float* __restrict__ bias, const float* __restrict__ resid,
        float* __restrict__ Cf, u16* __restrict__ Cb) {
    __shared__ u16 As[128 * 64];
    __shared__ u16 Bs[128 * 64];
    const int t = threadIdx.x;
    const int w = t >> 6;          // wave 0..3
    const int lane = t & 63;
    const int r = lane & 15, quad = lane >> 4;
    const int wm = w & 1, wn = w >> 1;
    const int m0 = blockIdx.x * 128;
    const int n0 = blockIdx.y * 128;

    f32x4 acc[4][4];
    #pragma unroll
    for (int mi = 0; mi < 4; ++mi)
        #pragma unroll
        for (int ni = 0; ni < 4; ++ni)
            acc[mi][ni] = (f32x4){0.f, 0.f, 0.f, 0.f};

    for (int k0 = 0; k0 < K; k0 += 64) {
        __syncthreads();   // previous iter's LDS reads done before overwrite
        // stage A-tile [128][64] and B-tile [128][64] (row-major, bf16).
        // 16B chunk c: row = c>>3, colchunk = c&7. Wave-instr i covers chunks
        // (i*4+w)*64 + lane; HW writes ldsbase + lane*16.
        #pragma unroll
        for (int i = 0; i < 4; ++i) {
            int chunk = (i * 4 + w) * 64 + lane;
            int row = chunk >> 3, cc = chunk & 7;
            const u16* ga = A + (size_t)(m0 + row) * K + k0 + cc * 8;
            const u16* gb = W + (size_t)(n0 + row) * K + k0 + cc * 8;
            __builtin_amdgcn_global_load_lds(
                (const __attribute__((address_space(1))) u32*)ga,
                (__attribute__((address_space(3))) u32*)(As + (i * 4 + w) * 512),
                16, 0, 0);
            __builtin_amdgcn_global_load_lds(
                (const __attribute__((address_space(1))) u32*)gb,
                (__attribute__((address_space(3))) u32*)(Bs + (i * 4 + w) * 512),
                16, 0, 0);
        }
        __syncthreads();   // staging visible
        #pragma unroll
        for (int kk = 0; kk < 2; ++kk) {
            bf16x8 af[4], bfr[4];
            #pragma unroll
            for (int mi = 0; mi < 4; ++mi)
                af[mi] = *(const bf16x8*)&As[(wm * 64 + mi * 16 + r) * 64 + kk * 32 + quad * 8];
            #pragma unroll
            for (int ni = 0; ni < 4; ++ni)
                bfr[ni] = *(const bf16x8*)&Bs[(wn * 64 + ni * 16 + r) * 64 + kk * 32 + quad * 8];
            #pragma unroll
            for (int mi = 0; mi < 4; ++mi)
                #pragma unroll
                for (int ni = 0; ni < 4; ++ni)
                    acc[mi][ni] = __builtin_amdgcn_mfma_f32_16x16x32_bf16(
                        af[mi], bfr[ni], acc[mi][ni], 0, 0, 0);
        }
    }
    // epilogue: C/D layout col = r, row = quad*4 + i
    #pragma unroll
    for (int mi = 0; mi < 4; ++mi) {
        #pragma unroll
        for (int i = 0; i < 4; ++i) {
            int row = m0 + wm * 64 + mi * 16 + quad * 4 + i;
            #pragma unroll
            for (int ni = 0; ni < 4; ++ni) {
                int col = n0 + wn * 64 + ni * 16 + r;
                size_t idx = (size_t)row * N + col;
                float v = acc[mi][ni][i];
                if (EPI == 2) { v += bias[col]; v = 0.5f * v * (1.0f + erff(v * 0.70710678118654752f)); }
                if (EPI == 3) { v += resid[idx]; }
                if (EPI == 4) { v += bias[col] + resid[idx]; }
                if (EPI == 2) Cb[idx] = f2bf(v);
                else          Cf[idx] = v;
            }
        }
    }
}

// ---------------- depthwise conv(K=4, pad left=1,right=2) + SiLU ----------
__global__ __launch_bounds__(256) void conv_silu_kernel(
        const float* __restrict__ xz,
        const float* __restrict__ wx, const float* __restrict__ bx,
        const float* __restrict__ wz, const float* __restrict__ bz,
        float* __restrict__ u_f, u16* __restrict__ u_bf,
        u16* __restrict__ ycat) {
    int c  = blockIdx.x * 256 + threadIdx.x;   // 0..1023
    int bl = blockIdx.y;                       // 0..B*L-1
    int l  = bl & (SEQ - 1);
    float accx = bx[c], accz = bz[c];
    #pragma unroll
    for (int k = 0; k < DCONV; ++k) {
        int lp = l + k - 1;
        if (lp >= 0 && lp < SEQ) {
            const float* rowp = xz + (size_t)(bl + (lp - l)) * DINNER;
            accx += rowp[c]        * wx[c * DCONV + k];
            accz += rowp[HALF + c] * wz[c * DCONV + k];
        }
    }
    float sx = accx / (1.f + expf(-accx));
    float sz = accz / (1.f + expf(-accz));
    size_t o = (size_t)bl * HALF + c;
    u_f[o]  = sx;
    u_bf[o] = f2bf(sx);
    ycat[(size_t)bl * DINNER + HALF + c] = f2bf(sz);
}

// ---------------- chunk-parallel selective scan ----------------
// h_l = exp(dl*Ac)*h_{l-1} + dl*B_l*u_l ;  y_l = sum_n C_l,n * h_l,n
// chunk decay = exp(Ac * sum(dl))  (product of exponentials).
// thread map p1/p3: t = ((b*NCH+ch)*HALF + d)*16 + n

__global__ __launch_bounds__(256) void scan_p1_kernel(
        const float* __restrict__ delta, const float* __restrict__ u_f,
        const float* __restrict__ x_dbl, const float* __restrict__ A_log,
        float* __restrict__ hfin, float* __restrict__ dsum) {
    int t  = blockIdx.x * 256 + threadIdx.x;
    int n  = t & 15;
    int d  = (t >> 4) & (HALF - 1);
    int ch = (t >> 14) & (NCH - 1);
    int b  = t >> 19;
    float Ac = -expf(A_log[d * DSTATE + n]);
    int l0 = ch * CL;
    size_t base_du = ((size_t)b * SEQ + l0) * HALF + d;
    size_t base_x  = ((size_t)b * SEQ + l0) * 96;
    float h = 0.f, ds = 0.f;
    for (int l = 0; l < CL; ++l) {
        float dl = delta[base_du + (size_t)l * HALF];
        float uv = u_f[base_du + (size_t)l * HALF];
        float Bv = x_dbl[base_x + (size_t)l * 96 + 64 + n];
        h = expf(dl * Ac) * h + dl * Bv * uv;
        ds += dl;
    }
    hfin[t] = h;
    if (n == 0) dsum[(b * NCH + ch) * HALF + d] = ds;
}

__global__ __launch_bounds__(256) void scan_p2_kernel(
        const float* __restrict__ A_log, const float* __restrict__ dsum,
        const float* __restrict__ hfin, float* __restrict__ hin) {
    int t = blockIdx.x * 256 + threadIdx.x;   // 0..B*HALF*16-1
    int n = t & 15;
    int d = (t >> 4) & (HALF - 1);
    int b = t >> 14;
    float Ac = -expf(A_log[d * DSTATE + n]);
    float h = 0.f;
    for (int ch = 0; ch < NCH; ++ch) {
        size_t idx = (((size_t)(b * NCH + ch) * HALF) + d) * 16 + n;
        hin[idx] = h;
        float ds = dsum[(b * NCH + ch) * HALF + d];
        h = expf(Ac * ds) * h + hfin[idx];
    }
}

__global__ __launch_bounds__(256) void scan_p3_kernel(
        const float* __restrict__ delta, const float* __restrict__ u_f,
        const float* __restrict__ x_dbl, const float* __restrict__ A_log,
        const float* __restrict__ Dp, const float* __restrict__ hin,
        u16* __restrict__ ycat) {
    int t  = blockIdx.x * 256 + threadIdx.x;
    int n  = t & 15;
    int d  = (t >> 4) & (HALF - 1);
    int ch = (t >> 14) & (NCH - 1);
    int b  = t >> 19;
    float Ac = -expf(A_log[d * DSTATE + n]);
    float Dv = Dp[d];
    int l0 = ch * CL;
    size_t base_du = ((size_t)b * SEQ + l0) * HALF + d;
    size_t base_x  = ((size_t)b * SEQ + l0) * 96;
    float h = hin[t];
    for (int l = 0; l < CL; ++l) {
        float dl = delta[base_du + (size_t)l * HALF];
        float uv = u_f[base_du + (size_t)l * HALF];
        float Bv = x_dbl[base_x + (size_t)l * 96 + 64 + n];
        float Cv = x_dbl[base_x + (size_t)l * 96 + 80 + n];
        h = expf(dl * Ac) * h + dl * Bv * uv;
        float contrib = h * Cv;
        contrib += __shfl_xor(contrib, 1, 64);
        contrib += __shfl_xor(contrib, 2, 64);
        contrib += __shfl_xor(contrib, 4, 64);
        contrib += __shfl_xor(contrib, 8, 64);
        if (n == 0)
            ycat[((size_t)(b * SEQ + l0 + l)) * DINNER + d] = f2bf(contrib + uv * Dv);
    }
}

// ---------------- host-side orchestration ----------------
extern "C" void kernel_launch(void* const* d_in, const int* in_sizes, int n_in,
                              void* d_out, int out_size, void* d_ws, size_t ws_size,
                              hipStream_t stream) {
    const float* x         = (const float*)d_in[0];
    const float* ln1_g     = (const float*)d_in[1];
    const float* ln1_b     = (const float*)d_in[2];
    const float* in_proj_w = (const float*)d_in[3];
    const float* conv_x_w  = (const float*)d_in[4];
    const float* conv_x_b  = (const float*)d_in[5];
    const float* conv_z_w  = (const float*)d_in[6];
    const float* conv_z_b  = (const float*)d_in[7];
    const float* x_proj_w  = (const float*)d_in[8];
    const float* dt_proj_w = (const float*)d_in[9];
    const float* dt_proj_b = (const float*)d_in[10];
    const float* A_log     = (const float*)d_in[11];
    const float* Dp        = (const float*)d_in[12];
    const float* out_proj_w= (const float*)d_in[13];
    const float* ln2_g     = (const float*)d_in[14];
    const float* ln2_b     = (const float*)d_in[15];
    const float* mlp_w1    = (const float*)d_in[16];
    const float* mlp_b1    = (const float*)d_in[17];
    const float* mlp_w2    = (const float*)d_in[18];
    const float* mlp_b2    = (const float*)d_in[19];
    float* out = (float*)d_out;

    char* p = (char*)d_ws;
    auto alloc = [&](size_t bytes) {
        char* r = p; p += (bytes + 255) & ~(size_t)255; return r;
    };
    u16*   w_in   = (u16*)  alloc((size_t)DINNER * DIMD * 2);
    u16*   w_xp   = (u16*)  alloc((size_t)96 * HALF * 2);
    u16*   w_dt   = (u16*)  alloc((size_t)HALF * DTRANK * 2);
    u16*   w_out  = (u16*)  alloc((size_t)DIMD * DINNER * 2);
    u16*   w_m1   = (u16*)  alloc((size_t)MLPD * DIMD * 2);
    u16*   w_m2   = (u16*)  alloc((size_t)DIMD * MLPD * 2);
    u16*   xn_bf  = (u16*)  alloc((size_t)NTOK * DIMD * 2);
    float* xz     = (float*)alloc((size_t)NTOK * DINNER * 4);
    float* u_f    = (float*)alloc((size_t)NTOK * HALF * 4);
    u16*   u_bf   = (u16*)  alloc((size_t)NTOK * HALF * 2);
    u16*   ycat   = (u16*)  alloc((size_t)NTOK * DINNER * 2);
    float* x_dbl  = (float*)alloc((size_t)NTOK * 96 * 4);
    u16*   xdbl_bf= (u16*)  alloc((size_t)NTOK * 96 * 2);
    float* delta  = (float*)alloc((size_t)NTOK * HALF * 4);
    float* x2     = (float*)alloc((size_t)NTOK * DIMD * 4);
    u16*   ln2_bf = (u16*)  alloc((size_t)NTOK * DIMD * 2);
    u16*   mlp_h  = (u16*)xz;    // alias: xz dead after conv
    // scan scratch aliases x2 (dead until out_proj, which runs after scan):
    float* hfin = x2;                                        // 4 MB
    float* hin  = x2 + (size_t)BSZ * NCH * HALF * DSTATE;    // 4 MB
    float* dsum = hin + (size_t)BSZ * NCH * HALF * DSTATE;   // 256 KB

    auto cvt = [&](const float* src, u16* dst, int n) {
        cvt_bf16_kernel<<<(n + 255) / 256, 256, 0, stream>>>(src, dst, n);
    };
    cvt(in_proj_w,  w_in,  DINNER * DIMD);
    cvt(x_proj_w,   w_xp,  96 * HALF);
    cvt(dt_proj_w,  w_dt,  HALF * DTRANK);
    cvt(out_proj_w, w_out, DIMD * DINNER);
    cvt(mlp_w1,     w_m1,  MLPD * DIMD);
    cvt(mlp_w2,     w_m2,  DIMD * MLPD);

    // LN1
    ln_bf16_kernel<<<NTOK, 256, 0, stream>>>(x, ln1_g, ln1_b, xn_bf);

    // in_proj: xz[4096,2048] = xn @ W^T
    gemm128_kernel<0><<<dim3(NTOK/128, DINNER/128), 256, 0, stream>>>(
        xn_bf, w_in, DIMD, DINNER, nullptr, nullptr, xz, nullptr);

    // depthwise conv + silu
    conv_silu_kernel<<<dim3(HALF/256, NTOK), 256, 0, stream>>>(
        xz, conv_x_w, conv_x_b, conv_z_w, conv_z_b, u_f, u_bf, ycat);

    // x_proj: [4096,96] = u @ W^T
    gemm_mfma_kernel<0><<<dim3(NTOK/16, 96/16), 64, 0, stream>>>(
        u_bf, HALF, w_xp, HALF, 96, nullptr, x_dbl);

    cvt(x_dbl, xdbl_bf, NTOK * 96);

    // dt_proj: delta = softplus(dt @ W^T + b)
    gemm_mfma_kernel<1><<<dim3(NTOK/16, HALF/16), 64, 0, stream>>>(
        xdbl_bf, 96, w_dt, DTRANK, HALF, dt_proj_b, delta);

    // chunk-parallel scan
    scan_p1_kernel<<<(BSZ*NCH*HALF*DSTATE)/256, 256, 0, stream>>>(
        delta, u_f, x_dbl, A_log, hfin, dsum);
    scan_p2_kernel<<<(BSZ*HALF*DSTATE)/256, 256, 0, stream>>>(
        A_log, dsum, hfin, hin);
    scan_p3_kernel<<<(BSZ*NCH*HALF*DSTATE)/256, 256, 0, stream>>>(
        delta, u_f, x_dbl, A_log, Dp, hin, ycat);

    // out_proj + residual: x2 = x + ycat @ W^T   (overwrites scan scratch - ok)
    gemm128_kernel<3><<<dim3(NTOK/128, DIMD/128), 256, 0, stream>>>(
        ycat, w_out, DINNER, DIMD, nullptr, x, x2, nullptr);

    // LN2
    ln_bf16_kernel<<<NTOK, 256, 0, stream>>>(x2, ln2_g, ln2_b, ln2_bf);

    // MLP1: gelu(ln2 @ W1^T + b1) -> bf16
    gemm128_kernel<2><<<dim3(NTOK/128, MLPD/128), 256, 0, stream>>>(
        ln2_bf, w_m1, DIMD, MLPD, mlp_b1, nullptr, nullptr, mlp_h);

    // MLP2 + residual: out = x2 + mlp_h @ W2^T + b2
    gemm128_kernel<4><<<dim3(NTOK/128, DIMD/128), 256, 0, stream>>>(
        mlp_h, w_m2, MLPD, DIMD, mlp_b2, x2, out, nullptr);
}

// Round 3
// 566.890 us; speedup vs baseline: 4.0185x; 1.0083x over previous
//
#include <hip/hip_runtime.h>
#include <math.h>

#define DIMD    1024
#define MLPD    4096
#define DSTATE  16
#define DCONV   4
#define HALF    1024
#define DINNER  2048
#define DTRANK  64
#define BSZ     2
#define SEQ     2048
#define NTOK    (BSZ*SEQ)   // 4096
#define NCH     32
#define CL      (SEQ/NCH)   // 64

typedef short bf16x8 __attribute__((ext_vector_type(8)));
typedef float f32x4  __attribute__((ext_vector_type(4)));
typedef unsigned short u16;
typedef unsigned int   u32;

__device__ __forceinline__ u16 f2bf(float x) {
    union { float f; unsigned int u; } v; v.f = x;
    unsigned int r = (v.u + 0x7FFFu + ((v.u >> 16) & 1u)) >> 16;
    return (u16)r;
}

// ---------------- f32 -> bf16 convert ----------------
__global__ __launch_bounds__(256) void cvt_bf16_kernel(
        const float* __restrict__ in, u16* __restrict__ out, int n) {
    int i = blockIdx.x * 256 + threadIdx.x;
    if (i < n) out[i] = f2bf(in[i]);
}

// ---------------- LayerNorm (row of 1024) -> bf16 ----------------
__global__ __launch_bounds__(256) void ln_bf16_kernel(
        const float* __restrict__ x, const float* __restrict__ g,
        const float* __restrict__ b, u16* __restrict__ out) {
    __shared__ float sm[4];
    int row = blockIdx.x;
    int t = threadIdx.x;          // 0..255, each owns 4 floats
    const float4* xr = (const float4*)(x + (size_t)row * DIMD);
    float4 v = xr[t];
    float s = v.x + v.y + v.z + v.w;
    for (int off = 32; off > 0; off >>= 1) s += __shfl_down(s, off, 64);
    if ((t & 63) == 0) sm[t >> 6] = s;
    __syncthreads();
    float mu = (sm[0] + sm[1] + sm[2] + sm[3]) * (1.0f / DIMD);
    float dx = v.x - mu, dy = v.y - mu, dz = v.z - mu, dw = v.w - mu;
    float ss = dx*dx + dy*dy + dz*dz + dw*dw;
    for (int off = 32; off > 0; off >>= 1) ss += __shfl_down(ss, off, 64);
    __syncthreads();
    if ((t & 63) == 0) sm[t >> 6] = ss;
    __syncthreads();
    float var = (sm[0] + sm[1] + sm[2] + sm[3]) * (1.0f / DIMD);
    float rs = rsqrtf(var + 1e-5f);
    float4 gv = ((const float4*)g)[t];
    float4 bv = ((const float4*)b)[t];
    u16* o = out + (size_t)row * DIMD + t * 4;
    o[0] = f2bf(dx * rs * gv.x + bv.x);
    o[1] = f2bf(dy * rs * gv.y + bv.y);
    o[2] = f2bf(dz * rs * gv.z + bv.z);
    o[3] = f2bf(dw * rs * gv.w + bv.w);
}

// ---------------- small GEMM (one wave, 16x16 tile): x_proj only ---------
__global__ __launch_bounds__(64) void gemm_small_kernel(
        const u16* __restrict__ A, int lda,
        const u16* __restrict__ W, int K, int N,
        float* __restrict__ Cf) {
    int m0 = blockIdx.x * 16;
    int n0 = blockIdx.y * 16;
    int lane = threadIdx.x;
    int r = lane & 15, quad = lane >> 4;
    f32x4 acc = {0.f, 0.f, 0.f, 0.f};
    const u16* ap = A + (size_t)(m0 + r) * lda + quad * 8;
    const u16* wp = W + (size_t)(n0 + r) * K   + quad * 8;
    for (int k = 0; k < K; k += 32) {
        bf16x8 av = *(const bf16x8*)(ap + k);
        bf16x8 bv = *(const bf16x8*)(wp + k);
        acc = __builtin_amdgcn_mfma_f32_16x16x32_bf16(av, bv, acc, 0, 0, 0);
    }
    int col = n0 + r;
    #pragma unroll
    for (int i = 0; i < 4; ++i) {
        int row = m0 + quad * 4 + i;
        Cf[(size_t)row * N + col] = acc[i];
    }
}

// ---------------- big GEMM: 128xTN tile, 4 waves, dbuf LDS, XOR swizzle ---
// C[M,N] = A[M,K] * W[N,K]^T, bf16 in, f32 acc. M%128==0, N%TN==0, K%64==0.
// EPI: 0 plain f32 | 1 bias+softplus f32 | 2 bias+gelu bf16
//      3 +resid f32 | 4 bias+resid f32
// LDS chunk swizzle: LDS position (row, q) holds global chunk (row, q^(row&7)).
// Staging permutes the global source (LDS dest is pinned to lane*16);
// fragment reads XOR the same pattern back.
template<int EPI, int TN>
__global__ __launch_bounds__(256) void gemm128_kernel(
        const u16* __restrict__ A, int lda, const u16* __restrict__ W,
        int K, int N,
        const float* __restrict__ bias, const float* __restrict__ resid,
        float* __restrict__ Cf, u16* __restrict__ Cb) {
    constexpr int NF = TN / 32;     // frags/wave along N; also B staging rounds
    __shared__ u16 As[2][128 * 64];
    __shared__ u16 Bs[2][TN * 64];
    const int t = threadIdx.x;
    const int w = t >> 6;           // wave 0..3
    const int lane = t & 63;
    const int r = lane & 15, quad = lane >> 4;
    const int wm = w & 1, wn = w >> 1;
    const int m0 = blockIdx.x * 128;
    const int n0 = blockIdx.y * TN;

    f32x4 acc[4][NF];
    #pragma unroll
    for (int mi = 0; mi < 4; ++mi)
        #pragma unroll
        for (int ni = 0; ni < NF; ++ni)
            acc[mi][ni] = (f32x4){0.f, 0.f, 0.f, 0.f};

    auto stage = [&](int buf, int k0) {
        #pragma unroll
        for (int i = 0; i < 4; ++i) {        // A: 128*8=1024 chunks, 4 rounds
            int chunk = (i * 4 + w) * 64 + lane;
            int row = chunk >> 3, q = chunk & 7;
            int qd = q ^ (row & 7);
            const u16* ga = A + (size_t)(m0 + row) * lda + k0 + qd * 8;
            __builtin_amdgcn_global_load_lds(
                (const __attribute__((address_space(1))) u32*)ga,
                (__attribute__((address_space(3))) u32*)(As[buf] + (i * 4 + w) * 512),
                16, 0, 0);
        }
        #pragma unroll
        for (int i = 0; i < NF; ++i) {       // B: TN*8 chunks, NF rounds
            int chunk = (i * 4 + w) * 64 + lane;
            int row = chunk >> 3, q = chunk & 7;
            int qd = q ^ (row & 7);
            const u16* gb = W + (size_t)(n0 + row) * K + k0 + qd * 8;
            __builtin_amdgcn_global_load_lds(
                (const __attribute__((address_space(1))) u32*)gb,
                (__attribute__((address_space(3))) u32*)(Bs[buf] + (i * 4 + w) * 512),
                16, 0, 0);
        }
    };

    stage(0, 0);
    int cur = 0;
    for (int k0 = 0; k0 < K; k0 += 64, cur ^= 1) {
        __syncthreads();   // drains staging into `cur`; fences prev reads
        if (k0 + 64 < K) stage(cur ^ 1, k0 + 64);
        #pragma unroll
        for (int kk = 0; kk < 2; ++kk) {
            bf16x8 af[4], bfr[NF];
            #pragma unroll
            for (int mi = 0; mi < 4; ++mi) {
                int row = wm * 64 + mi * 16 + r;
                int qx = (kk * 4 + quad) ^ (r & 7);
                af[mi] = *(const bf16x8*)&As[cur][row * 64 + qx * 8];
            }
            #pragma unroll
            for (int ni = 0; ni < NF; ++ni) {
                int row = wn * (TN / 2) + ni * 16 + r;
                int qx = (kk * 4 + quad) ^ (r & 7);
                bfr[ni] = *(const bf16x8*)&Bs[cur][row * 64 + qx * 8];
            }
            #pragma unroll
            for (int mi = 0; mi < 4; ++mi)
                #pragma unroll
                for (int ni = 0; ni < NF; ++ni)
                    acc[mi][ni] = __builtin_amdgcn_mfma_f32_16x16x32_bf16(
                        af[mi], bfr[ni], acc[mi][ni], 0, 0, 0);
        }
    }
    // epilogue: C/D layout col = r, row = quad*4 + i
    #pragma unroll
    for (int mi = 0; mi < 4; ++mi) {
        #pragma unroll
        for (int i = 0; i < 4; ++i) {
            int row = m0 + wm * 64 + mi * 16 + quad * 4 + i;
            #pragma unroll
            for (int ni = 0; ni < NF; ++ni) {
                int col = n0 + wn * (TN / 2) + ni * 16 + r;
                size_t idx = (size_t)row * N + col;
                float v = acc[mi][ni][i];
                if (EPI == 1) { v += bias[col]; v = (v > 20.f) ? v : log1pf(expf(v)); }
                if (EPI == 2) { v += bias[col]; v = 0.5f * v * (1.0f + erff(v * 0.70710678118654752f)); }
                if (EPI == 3) { v += resid[idx]; }
                if (EPI == 4) { v += bias[col] + resid[idx]; }
                if (EPI == 2) Cb[idx] = f2bf(v);
                else          Cf[idx] = v;
            }
        }
    }
}

// ---------------- depthwise conv(K=4, pad left=1,right=2) + SiLU ----------
__global__ __launch_bounds__(256) void conv_silu_kernel(
        const float* __restrict__ xz,
        const float* __restrict__ wx, const float* __restrict__ bx,
        const float* __restrict__ wz, const float* __restrict__ bz,
        float* __restrict__ u_f, u16* __restrict__ u_bf,
        u16* __restrict__ ycat) {
    int c  = blockIdx.x * 256 + threadIdx.x;   // 0..1023
    int bl = blockIdx.y;                       // 0..B*L-1
    int l  = bl & (SEQ - 1);
    float accx = bx[c], accz = bz[c];
    #pragma unroll
    for (int k = 0; k < DCONV; ++k) {
        int lp = l + k - 1;
        if (lp >= 0 && lp < SEQ) {
            const float* rowp = xz + (size_t)(bl + (lp - l)) * DINNER;
            accx += rowp[c]        * wx[c * DCONV + k];
            accz += rowp[HALF + c] * wz[c * DCONV + k];
        }
    }
    float sx = accx / (1.f + expf(-accx));
    float sz = accz / (1.f + expf(-accz));
    size_t o = (size_t)bl * HALF + c;
    u_f[o]  = sx;
    u_bf[o] = f2bf(sx);
    ycat[(size_t)bl * DINNER + HALF + c] = f2bf(sz);
}

// ---------------- chunk-parallel selective scan ----------------
__global__ __launch_bounds__(256) void scan_p1_kernel(
        const float* __restrict__ delta, const float* __restrict__ u_f,
        const float* __restrict__ x_dbl, const float* __restrict__ A_log,
        float* __restrict__ hfin, float* __restrict__ dsum) {
    int t  = blockIdx.x * 256 + threadIdx.x;
    int n  = t & 15;
    int d  = (t >> 4) & (HALF - 1);
    int ch = (t >> 14) & (NCH - 1);
    int b  = t >> 19;
    float Ac = -expf(A_log[d * DSTATE + n]);
    int l0 = ch * CL;
    size_t base_du = ((size_t)b * SEQ + l0) * HALF + d;
    size_t base_x  = ((size_t)b * SEQ + l0) * 96;
    float h = 0.f, ds = 0.f;
    for (int l = 0; l < CL; ++l) {
        float dl = delta[base_du + (size_t)l * HALF];
        float uv = u_f[base_du + (size_t)l * HALF];
        float Bv = x_dbl[base_x + (size_t)l * 96 + 64 + n];
        h = expf(dl * Ac) * h + dl * Bv * uv;
        ds += dl;
    }
    hfin[t] = h;
    if (n == 0) dsum[(b * NCH + ch) * HALF + d] = ds;
}

__global__ __launch_bounds__(256) void scan_p2_kernel(
        const float* __restrict__ A_log, const float* __restrict__ dsum,
        const float* __restrict__ hfin, float* __restrict__ hin) {
    int t = blockIdx.x * 256 + threadIdx.x;   // 0..B*HALF*16-1
    int n = t & 15;
    int d = (t >> 4) & (HALF - 1);
    int b = t >> 14;
    float Ac = -expf(A_log[d * DSTATE + n]);
    float h = 0.f;
    for (int ch = 0; ch < NCH; ++ch) {
        size_t idx = (((size_t)(b * NCH + ch) * HALF) + d) * 16 + n;
        hin[idx] = h;
        float ds = dsum[(b * NCH + ch) * HALF + d];
        h = expf(Ac * ds) * h + hfin[idx];
    }
}

__global__ __launch_bounds__(256) void scan_p3_kernel(
        const float* __restrict__ delta, const float* __restrict__ u_f,
        const float* __restrict__ x_dbl, const float* __restrict__ A_log,
        const float* __restrict__ Dp, const float* __restrict__ hin,
        u16* __restrict__ ycat) {
    int t  = blockIdx.x * 256 + threadIdx.x;
    int n  = t & 15;
    int d  = (t >> 4) & (HALF - 1);
    int ch = (t >> 14) & (NCH - 1);
    int b  = t >> 19;
    float Ac = -expf(A_log[d * DSTATE + n]);
    float Dv = Dp[d];
    int l0 = ch * CL;
    size_t base_du = ((size_t)b * SEQ + l0) * HALF + d;
    size_t base_x  = ((size_t)b * SEQ + l0) * 96;
    float h = hin[t];
    for (int l = 0; l < CL; ++l) {
        float dl = delta[base_du + (size_t)l * HALF];
        float uv = u_f[base_du + (size_t)l * HALF];
        float Bv = x_dbl[base_x + (size_t)l * 96 + 64 + n];
        float Cv = x_dbl[base_x + (size_t)l * 96 + 80 + n];
        h = expf(dl * Ac) * h + dl * Bv * uv;
        float contrib = h * Cv;
        contrib += __shfl_xor(contrib, 1, 64);
        contrib += __shfl_xor(contrib, 2, 64);
        contrib += __shfl_xor(contrib, 4, 64);
        contrib += __shfl_xor(contrib, 8, 64);
        if (n == 0)
            ycat[((size_t)(b * SEQ + l0 + l)) * DINNER + d] = f2bf(contrib + uv * Dv);
    }
}

// ---------------- host-side orchestration ----------------
extern "C" void kernel_launch(void* const* d_in, const int* in_sizes, int n_in,
                              void* d_out, int out_size, void* d_ws, size_t ws_size,
                              hipStream_t stream) {
    const float* x         = (const float*)d_in[0];
    const float* ln1_g     = (const float*)d_in[1];
    const float* ln1_b     = (const float*)d_in[2];
    const float* in_proj_w = (const float*)d_in[3];
    const float* conv_x_w  = (const float*)d_in[4];
    const float* conv_x_b  = (const float*)d_in[5];
    const float* conv_z_w  = (const float*)d_in[6];
    const float* conv_z_b  = (const float*)d_in[7];
    const float* x_proj_w  = (const float*)d_in[8];
    const float* dt_proj_w = (const float*)d_in[9];
    const float* dt_proj_b = (const float*)d_in[10];
    const float* A_log     = (const float*)d_in[11];
    const float* Dp        = (const float*)d_in[12];
    const float* out_proj_w= (const float*)d_in[13];
    const float* ln2_g     = (const float*)d_in[14];
    const float* ln2_b     = (const float*)d_in[15];
    const float* mlp_w1    = (const float*)d_in[16];
    const float* mlp_b1    = (const float*)d_in[17];
    const float* mlp_w2    = (const float*)d_in[18];
    const float* mlp_b2    = (const float*)d_in[19];
    float* out = (float*)d_out;

    char* p = (char*)d_ws;
    auto alloc = [&](size_t bytes) {
        char* r = p; p += (bytes + 255) & ~(size_t)255; return r;
    };
    u16*   w_in   = (u16*)  alloc((size_t)DINNER * DIMD * 2);
    u16*   w_xp   = (u16*)  alloc((size_t)96 * HALF * 2);
    u16*   w_dt   = (u16*)  alloc((size_t)HALF * DTRANK * 2);
    u16*   w_out  = (u16*)  alloc((size_t)DIMD * DINNER * 2);
    u16*   w_m1   = (u16*)  alloc((size_t)MLPD * DIMD * 2);
    u16*   w_m2   = (u16*)  alloc((size_t)DIMD * MLPD * 2);
    u16*   xn_bf  = (u16*)  alloc((size_t)NTOK * DIMD * 2);
    float* xz     = (float*)alloc((size_t)NTOK * DINNER * 4);
    float* u_f    = (float*)alloc((size_t)NTOK * HALF * 4);
    u16*   u_bf   = (u16*)  alloc((size_t)NTOK * HALF * 2);
    u16*   ycat   = (u16*)  alloc((size_t)NTOK * DINNER * 2);
    float* x_dbl  = (float*)alloc((size_t)NTOK * 96 * 4);
    u16*   xdbl_bf= (u16*)  alloc((size_t)NTOK * 96 * 2);
    float* delta  = (float*)alloc((size_t)NTOK * HALF * 4);
    float* x2     = (float*)alloc((size_t)NTOK * DIMD * 4);
    u16*   ln2_bf = (u16*)  alloc((size_t)NTOK * DIMD * 2);
    u16*   mlp_h  = (u16*)xz;    // alias: xz dead after conv
    // scan scratch aliases x2 (dead until out_proj, which runs after scan):
    float* hfin = x2;                                        // 4 MB
    float* hin  = x2 + (size_t)BSZ * NCH * HALF * DSTATE;    // 4 MB
    float* dsum = hin + (size_t)BSZ * NCH * HALF * DSTATE;   // 256 KB

    auto cvt = [&](const float* src, u16* dst, int n) {
        cvt_bf16_kernel<<<(n + 255) / 256, 256, 0, stream>>>(src, dst, n);
    };
    cvt(in_proj_w,  w_in,  DINNER * DIMD);
    cvt(x_proj_w,   w_xp,  96 * HALF);
    cvt(dt_proj_w,  w_dt,  HALF * DTRANK);
    cvt(out_proj_w, w_out, DIMD * DINNER);
    cvt(mlp_w1,     w_m1,  MLPD * DIMD);
    cvt(mlp_w2,     w_m2,  DIMD * MLPD);

    // LN1
    ln_bf16_kernel<<<NTOK, 256, 0, stream>>>(x, ln1_g, ln1_b, xn_bf);

    // in_proj: xz[4096,2048] = xn @ W^T
    gemm128_kernel<0,128><<<dim3(NTOK/128, DINNER/128), 256, 0, stream>>>(
        xn_bf, DIMD, w_in, DIMD, DINNER, nullptr, nullptr, xz, nullptr);

    // depthwise conv + silu
    conv_silu_kernel<<<dim3(HALF/256, NTOK), 256, 0, stream>>>(
        xz, conv_x_w, conv_x_b, conv_z_w, conv_z_b, u_f, u_bf, ycat);

    // x_proj: [4096,96] = u @ W^T
    gemm_small_kernel<<<dim3(NTOK/16, 96/16), 64, 0, stream>>>(
        u_bf, HALF, w_xp, HALF, 96, x_dbl);

    cvt(x_dbl, xdbl_bf, NTOK * 96);

    // dt_proj: delta = softplus(dt @ W^T + b)  (lda=96, K=64)
    gemm128_kernel<1,64><<<dim3(NTOK/128, HALF/64), 256, 0, stream>>>(
        xdbl_bf, 96, w_dt, DTRANK, HALF, dt_proj_b, nullptr, delta, nullptr);

    // chunk-parallel scan
    scan_p1_kernel<<<(BSZ*NCH*HALF*DSTATE)/256, 256, 0, stream>>>(
        delta, u_f, x_dbl, A_log, hfin, dsum);
    scan_p2_kernel<<<(BSZ*HALF*DSTATE)/256, 256, 0, stream>>>(
        A_log, dsum, hfin, hin);
    scan_p3_kernel<<<(BSZ*NCH*HALF*DSTATE)/256, 256, 0, stream>>>(
        delta, u_f, x_dbl, A_log, Dp, hin, ycat);

    // out_proj + residual: x2 = x + ycat @ W^T  (TN=64: 512 blocks)
    gemm128_kernel<3,64><<<dim3(NTOK/128, DIMD/64), 256, 0, stream>>>(
        ycat, DINNER, w_out, DINNER, DIMD, nullptr, x, x2, nullptr);

    // LN2
    ln_bf16_kernel<<<NTOK, 256, 0, stream>>>(x2, ln2_g, ln2_b, ln2_bf);

    // MLP1: gelu(ln2 @ W1^T + b1) -> bf16
    gemm128_kernel<2,128><<<dim3(NTOK/128, MLPD/128), 256, 0, stream>>>(
        ln2_bf, DIMD, w_m1, DIMD, MLPD, mlp_b1, nullptr, nullptr, mlp_h);

    // MLP2 + residual: out = x2 + mlp_h @ W2^T + b2  (TN=64: 512 blocks)
    gemm128_kernel<4,64><<<dim3(NTOK/128, DIMD/64), 256, 0, stream>>>(
        mlp_h, MLPD, w_m2, MLPD, DIMD, mlp_b2, x2, out, nullptr);
}

// Round 4
// 537.640 us; speedup vs baseline: 4.2371x; 1.0544x over previous
//
#include <hip/hip_runtime.h>
#include <math.h>

#define DIMD    1024
#define MLPD    4096
#define DSTATE  16
#define DCONV   4
#define HALF    1024
#define DINNER  2048
#define DTRANK  64
#define BSZ     2
#define SEQ     2048
#define NTOK    (BSZ*SEQ)   // 4096
#define NCH     32
#define CL      (SEQ/NCH)   // 64

typedef short bf16x8 __attribute__((ext_vector_type(8)));
typedef float f32x4  __attribute__((ext_vector_type(4)));
typedef unsigned short u16;
typedef unsigned int   u32;

__device__ __forceinline__ u16 f2bf(float x) {
    union { float f; unsigned int u; } v; v.f = x;
    unsigned int r = (v.u + 0x7FFFu + ((v.u >> 16) & 1u)) >> 16;
    return (u16)r;
}

// ---------------- fused weight f32 -> bf16 convert (6 segments) ----------
#define SZ_WIN  (DINNER*DIMD)   // 2097152
#define SZ_WXP  (96*HALF)       // 98304
#define SZ_WDT  (HALF*DTRANK)   // 65536
#define SZ_WOUT (DIMD*DINNER)   // 2097152
#define SZ_WM1  (MLPD*DIMD)     // 4194304
#define SZ_WM2  (DIMD*MLPD)     // 4194304
#define SZ_TOT  (SZ_WIN+SZ_WXP+SZ_WDT+SZ_WOUT+SZ_WM1+SZ_WM2)  // 12746752

__global__ __launch_bounds__(256) void cvt6_kernel(
        const float* __restrict__ s0, u16* __restrict__ d0,
        const float* __restrict__ s1, u16* __restrict__ d1,
        const float* __restrict__ s2, u16* __restrict__ d2,
        const float* __restrict__ s3, u16* __restrict__ d3,
        const float* __restrict__ s4, u16* __restrict__ d4,
        const float* __restrict__ s5, u16* __restrict__ d5) {
    int i = blockIdx.x * 256 + threadIdx.x;
    if (i < SZ_WIN)  { d0[i] = f2bf(s0[i]); return; }  i -= SZ_WIN;
    if (i < SZ_WXP)  { d1[i] = f2bf(s1[i]); return; }  i -= SZ_WXP;
    if (i < SZ_WDT)  { d2[i] = f2bf(s2[i]); return; }  i -= SZ_WDT;
    if (i < SZ_WOUT) { d3[i] = f2bf(s3[i]); return; }  i -= SZ_WOUT;
    if (i < SZ_WM1)  { d4[i] = f2bf(s4[i]); return; }  i -= SZ_WM1;
    d5[i] = f2bf(s5[i]);
}

// ---------------- LayerNorm (row of 1024) -> bf16 ----------------
__global__ __launch_bounds__(256) void ln_bf16_kernel(
        const float* __restrict__ x, const float* __restrict__ g,
        const float* __restrict__ b, u16* __restrict__ out) {
    __shared__ float sm[4];
    int row = blockIdx.x;
    int t = threadIdx.x;          // 0..255, each owns 4 floats
    const float4* xr = (const float4*)(x + (size_t)row * DIMD);
    float4 v = xr[t];
    float s = v.x + v.y + v.z + v.w;
    for (int off = 32; off > 0; off >>= 1) s += __shfl_down(s, off, 64);
    if ((t & 63) == 0) sm[t >> 6] = s;
    __syncthreads();
    float mu = (sm[0] + sm[1] + sm[2] + sm[3]) * (1.0f / DIMD);
    float dx = v.x - mu, dy = v.y - mu, dz = v.z - mu, dw = v.w - mu;
    float ss = dx*dx + dy*dy + dz*dz + dw*dw;
    for (int off = 32; off > 0; off >>= 1) ss += __shfl_down(ss, off, 64);
    __syncthreads();
    if ((t & 63) == 0) sm[t >> 6] = ss;
    __syncthreads();
    float var = (sm[0] + sm[1] + sm[2] + sm[3]) * (1.0f / DIMD);
    float rs = rsqrtf(var + 1e-5f);
    float4 gv = ((const float4*)g)[t];
    float4 bv = ((const float4*)b)[t];
    u16* o = out + (size_t)row * DIMD + t * 4;
    o[0] = f2bf(dx * rs * gv.x + bv.x);
    o[1] = f2bf(dy * rs * gv.y + bv.y);
    o[2] = f2bf(dz * rs * gv.z + bv.z);
    o[3] = f2bf(dw * rs * gv.w + bv.w);
}

// ---------------- small GEMM (one wave, 16x16 tile): x_proj only ---------
// writes f32 AND bf16 outputs (bf16 feeds dt_proj)
__global__ __launch_bounds__(64) void gemm_small_kernel(
        const u16* __restrict__ A, int lda,
        const u16* __restrict__ W, int K, int N,
        float* __restrict__ Cf, u16* __restrict__ Cb) {
    int m0 = blockIdx.x * 16;
    int n0 = blockIdx.y * 16;
    int lane = threadIdx.x;
    int r = lane & 15, quad = lane >> 4;
    f32x4 acc = {0.f, 0.f, 0.f, 0.f};
    const u16* ap = A + (size_t)(m0 + r) * lda + quad * 8;
    const u16* wp = W + (size_t)(n0 + r) * K   + quad * 8;
    for (int k = 0; k < K; k += 32) {
        bf16x8 av = *(const bf16x8*)(ap + k);
        bf16x8 bv = *(const bf16x8*)(wp + k);
        acc = __builtin_amdgcn_mfma_f32_16x16x32_bf16(av, bv, acc, 0, 0, 0);
    }
    int col = n0 + r;
    #pragma unroll
    for (int i = 0; i < 4; ++i) {
        int row = m0 + quad * 4 + i;
        size_t idx = (size_t)row * N + col;
        Cf[idx] = acc[i];
        Cb[idx] = f2bf(acc[i]);
    }
}

// ---------------- big GEMM: 128xTN tile, BK=32, dbuf LDS, XOR swizzle ----
// C[M,N] = A[M,K] * W[N,K]^T, bf16 in, f32 acc. M%128==0, N%TN==0, K%32==0.
// EPI: 0 plain f32 | 1 bias+softplus f32 | 2 bias+gelu bf16
//      3 +resid f32 | 4 bias+resid f32
// LDS row = 32 bf16 = 64 B (16 banks). Chunk slot swizzle within a row:
// slot q holds global chunk q ^ ((row>>1)&3); read side XORs the same.
// Per quad-phase: 2 lanes per 4-bank slot -> conflict-free (m136).
template<int EPI, int TN>
__global__ __launch_bounds__(256) void gemm128_kernel(
        const u16* __restrict__ A, int lda, const u16* __restrict__ W,
        int K, int N,
        const float* __restrict__ bias, const float* __restrict__ resid,
        float* __restrict__ Cf, u16* __restrict__ Cb) {
    constexpr int NF = TN / 32;     // MFMA frags per wave along N
    __shared__ u16 As[2][128 * 32];
    __shared__ u16 Bs[2][TN * 32];
    const int t = threadIdx.x;
    const int w = t >> 6;           // wave 0..3
    const int lane = t & 63;
    const int r = lane & 15, quad = lane >> 4;
    const int wm = w & 1, wn = w >> 1;
    const int m0 = blockIdx.x * 128;
    const int n0 = blockIdx.y * TN;

    f32x4 acc[4][NF];
    #pragma unroll
    for (int mi = 0; mi < 4; ++mi)
        #pragma unroll
        for (int ni = 0; ni < NF; ++ni)
            acc[mi][ni] = (f32x4){0.f, 0.f, 0.f, 0.f};

    auto stage = [&](int buf, int k0) {
        // A-tile: 128 rows x 32 cols = 512 16B-chunks (4/row), 2 instr/wave
        #pragma unroll
        for (int i = 0; i < 2; ++i) {
            int c = (i * 4 + w) * 64 + lane;
            int row = c >> 2;
            int q = (c & 3) ^ ((row >> 1) & 3);
            const u16* ga = A + (size_t)(m0 + row) * lda + k0 + q * 8;
            __builtin_amdgcn_global_load_lds(
                (const __attribute__((address_space(1))) u32*)ga,
                (__attribute__((address_space(3))) u32*)(As[buf] + (i * 4 + w) * 512),
                16, 0, 0);
        }
        // B-tile: TN rows x 32 cols = TN*4 chunks, NF/2 instr/wave
        #pragma unroll
        for (int i = 0; i < NF / 2; ++i) {
            int c = (i * 4 + w) * 64 + lane;
            int row = c >> 2;
            int q = (c & 3) ^ ((row >> 1) & 3);
            const u16* gb = W + (size_t)(n0 + row) * K + k0 + q * 8;
            __builtin_amdgcn_global_load_lds(
                (const __attribute__((address_space(1))) u32*)gb,
                (__attribute__((address_space(3))) u32*)(Bs[buf] + (i * 4 + w) * 512),
                16, 0, 0);
        }
    };

    stage(0, 0);
    int cur = 0;
    for (int k0 = 0; k0 < K; k0 += 32, cur ^= 1) {
        __syncthreads();    // drains stage(cur) (issued one compute-phase ago)
        if (k0 + 32 < K) stage(cur ^ 1, k0 + 32);   // prefetch next tile
        const int qs = quad ^ ((r >> 1) & 3);
        bf16x8 af[4], bfr[NF];
        #pragma unroll
        for (int mi = 0; mi < 4; ++mi) {
            int row = wm * 64 + mi * 16 + r;
            af[mi] = *(const bf16x8*)&As[cur][row * 32 + qs * 8];
        }
        #pragma unroll
        for (int ni = 0; ni < NF; ++ni) {
            int row = wn * (TN / 2) + ni * 16 + r;
            bfr[ni] = *(const bf16x8*)&Bs[cur][row * 32 + qs * 8];
        }
        #pragma unroll
        for (int mi = 0; mi < 4; ++mi)
            #pragma unroll
            for (int ni = 0; ni < NF; ++ni)
                acc[mi][ni] = __builtin_amdgcn_mfma_f32_16x16x32_bf16(
                    af[mi], bfr[ni], acc[mi][ni], 0, 0, 0);
    }
    // epilogue: C/D layout col = r, row = quad*4 + i
    #pragma unroll
    for (int mi = 0; mi < 4; ++mi) {
        #pragma unroll
        for (int i = 0; i < 4; ++i) {
            int row = m0 + wm * 64 + mi * 16 + quad * 4 + i;
            #pragma unroll
            for (int ni = 0; ni < NF; ++ni) {
                int col = n0 + wn * (TN / 2) + ni * 16 + r;
                size_t idx = (size_t)row * N + col;
                float v = acc[mi][ni][i];
                if (EPI == 1) { v += bias[col]; v = (v > 20.f) ? v : log1pf(expf(v)); }
                if (EPI == 2) { v += bias[col]; v = 0.5f * v * (1.0f + erff(v * 0.70710678118654752f)); }
                if (EPI == 3) { v += resid[idx]; }
                if (EPI == 4) { v += bias[col] + resid[idx]; }
                if (EPI == 2) Cb[idx] = f2bf(v);
                else          Cf[idx] = v;
            }
        }
    }
}

// ---------------- depthwise conv(K=4, pad left=1,right=2) + SiLU ----------
__global__ __launch_bounds__(256) void conv_silu_kernel(
        const float* __restrict__ xz,
        const float* __restrict__ wx, const float* __restrict__ bx,
        const float* __restrict__ wz, const float* __restrict__ bz,
        float* __restrict__ u_f, u16* __restrict__ u_bf,
        u16* __restrict__ ycat) {
    int c  = blockIdx.x * 256 + threadIdx.x;   // 0..1023
    int bl = blockIdx.y;                       // 0..B*L-1
    int l  = bl & (SEQ - 1);
    float accx = bx[c], accz = bz[c];
    #pragma unroll
    for (int k = 0; k < DCONV; ++k) {
        int lp = l + k - 1;
        if (lp >= 0 && lp < SEQ) {
            const float* rowp = xz + (size_t)(bl + (lp - l)) * DINNER;
            accx += rowp[c]        * wx[c * DCONV + k];
            accz += rowp[HALF + c] * wz[c * DCONV + k];
        }
    }
    float sx = accx / (1.f + expf(-accx));
    float sz = accz / (1.f + expf(-accz));
    size_t o = (size_t)bl * HALF + c;
    u_f[o]  = sx;
    u_bf[o] = f2bf(sx);
    ycat[(size_t)bl * DINNER + HALF + c] = f2bf(sz);
}

// ---------------- chunk-parallel selective scan ----------------
__global__ __launch_bounds__(256) void scan_p1_kernel(
        const float* __restrict__ delta, const float* __restrict__ u_f,
        const float* __restrict__ x_dbl, const float* __restrict__ A_log,
        float* __restrict__ hfin, float* __restrict__ dsum) {
    int t  = blockIdx.x * 256 + threadIdx.x;
    int n  = t & 15;
    int d  = (t >> 4) & (HALF - 1);
    int ch = (t >> 14) & (NCH - 1);
    int b  = t >> 19;
    float Ac = -expf(A_log[d * DSTATE + n]);
    int l0 = ch * CL;
    size_t base_du = ((size_t)b * SEQ + l0) * HALF + d;
    size_t base_x  = ((size_t)b * SEQ + l0) * 96;
    float h = 0.f, ds = 0.f;
    for (int l = 0; l < CL; ++l) {
        float dl = delta[base_du + (size_t)l * HALF];
        float uv = u_f[base_du + (size_t)l * HALF];
        float Bv = x_dbl[base_x + (size_t)l * 96 + 64 + n];
        h = expf(dl * Ac) * h + dl * Bv * uv;
        ds += dl;
    }
    hfin[t] = h;
    if (n == 0) dsum[(b * NCH + ch) * HALF + d] = ds;
}

__global__ __launch_bounds__(256) void scan_p2_kernel(
        const float* __restrict__ A_log, const float* __restrict__ dsum,
        const float* __restrict__ hfin, float* __restrict__ hin) {
    int t = blockIdx.x * 256 + threadIdx.x;   // 0..B*HALF*16-1
    int n = t & 15;
    int d = (t >> 4) & (HALF - 1);
    int b = t >> 14;
    float Ac = -expf(A_log[d * DSTATE + n]);
    float h = 0.f;
    for (int ch = 0; ch < NCH; ++ch) {
        size_t idx = (((size_t)(b * NCH + ch) * HALF) + d) * 16 + n;
        hin[idx] = h;
        float ds = dsum[(b * NCH + ch) * HALF + d];
        h = expf(Ac * ds) * h + hfin[idx];
    }
}

__global__ __launch_bounds__(256) void scan_p3_kernel(
        const float* __restrict__ delta, const float* __restrict__ u_f,
        const float* __restrict__ x_dbl, const float* __restrict__ A_log,
        const float* __restrict__ Dp, const float* __restrict__ hin,
        u16* __restrict__ ycat) {
    int t  = blockIdx.x * 256 + threadIdx.x;
    int n  = t & 15;
    int d  = (t >> 4) & (HALF - 1);
    int ch = (t >> 14) & (NCH - 1);
    int b  = t >> 19;
    float Ac = -expf(A_log[d * DSTATE + n]);
    float Dv = Dp[d];
    int l0 = ch * CL;
    size_t base_du = ((size_t)b * SEQ + l0) * HALF + d;
    size_t base_x  = ((size_t)b * SEQ + l0) * 96;
    float h = hin[t];
    for (int l = 0; l < CL; ++l) {
        float dl = delta[base_du + (size_t)l * HALF];
        float uv = u_f[base_du + (size_t)l * HALF];
        float Bv = x_dbl[base_x + (size_t)l * 96 + 64 + n];
        float Cv = x_dbl[base_x + (size_t)l * 96 + 80 + n];
        h = expf(dl * Ac) * h + dl * Bv * uv;
        float contrib = h * Cv;
        contrib += __shfl_xor(contrib, 1, 64);
        contrib += __shfl_xor(contrib, 2, 64);
        contrib += __shfl_xor(contrib, 4, 64);
        contrib += __shfl_xor(contrib, 8, 64);
        if (n == 0)
            ycat[((size_t)(b * SEQ + l0 + l)) * DINNER + d] = f2bf(contrib + uv * Dv);
    }
}

// ---------------- host-side orchestration ----------------
extern "C" void kernel_launch(void* const* d_in, const int* in_sizes, int n_in,
                              void* d_out, int out_size, void* d_ws, size_t ws_size,
                              hipStream_t stream) {
    const float* x         = (const float*)d_in[0];
    const float* ln1_g     = (const float*)d_in[1];
    const float* ln1_b     = (const float*)d_in[2];
    const float* in_proj_w = (const float*)d_in[3];
    const float* conv_x_w  = (const float*)d_in[4];
    const float* conv_x_b  = (const float*)d_in[5];
    const float* conv_z_w  = (const float*)d_in[6];
    const float* conv_z_b  = (const float*)d_in[7];
    const float* x_proj_w  = (const float*)d_in[8];
    const float* dt_proj_w = (const float*)d_in[9];
    const float* dt_proj_b = (const float*)d_in[10];
    const float* A_log     = (const float*)d_in[11];
    const float* Dp        = (const float*)d_in[12];
    const float* out_proj_w= (const float*)d_in[13];
    const float* ln2_g     = (const float*)d_in[14];
    const float* ln2_b     = (const float*)d_in[15];
    const float* mlp_w1    = (const float*)d_in[16];
    const float* mlp_b1    = (const float*)d_in[17];
    const float* mlp_w2    = (const float*)d_in[18];
    const float* mlp_b2    = (const float*)d_in[19];
    float* out = (float*)d_out;

    char* p = (char*)d_ws;
    auto alloc = [&](size_t bytes) {
        char* r = p; p += (bytes + 255) & ~(size_t)255; return r;
    };
    u16*   w_in   = (u16*)  alloc((size_t)DINNER * DIMD * 2);
    u16*   w_xp   = (u16*)  alloc((size_t)96 * HALF * 2);
    u16*   w_dt   = (u16*)  alloc((size_t)HALF * DTRANK * 2);
    u16*   w_out  = (u16*)  alloc((size_t)DIMD * DINNER * 2);
    u16*   w_m1   = (u16*)  alloc((size_t)MLPD * DIMD * 2);
    u16*   w_m2   = (u16*)  alloc((size_t)DIMD * MLPD * 2);
    u16*   xn_bf  = (u16*)  alloc((size_t)NTOK * DIMD * 2);
    float* xz     = (float*)alloc((size_t)NTOK * DINNER * 4);
    float* u_f    = (float*)alloc((size_t)NTOK * HALF * 4);
    u16*   u_bf   = (u16*)  alloc((size_t)NTOK * HALF * 2);
    u16*   ycat   = (u16*)  alloc((size_t)NTOK * DINNER * 2);
    float* x_dbl  = (float*)alloc((size_t)NTOK * 96 * 4);
    u16*   xdbl_bf= (u16*)  alloc((size_t)NTOK * 96 * 2);
    float* delta  = (float*)alloc((size_t)NTOK * HALF * 4);
    float* x2     = (float*)alloc((size_t)NTOK * DIMD * 4);
    u16*   ln2_bf = (u16*)  alloc((size_t)NTOK * DIMD * 2);
    u16*   mlp_h  = (u16*)xz;    // alias: xz dead after conv
    // scan scratch aliases x2 (dead until out_proj, which runs after scan):
    float* hfin = x2;                                        // 4 MB
    float* hin  = x2 + (size_t)BSZ * NCH * HALF * DSTATE;    // 4 MB
    float* dsum = hin + (size_t)BSZ * NCH * HALF * DSTATE;   // 256 KB

    // all weight conversions in one dispatch
    cvt6_kernel<<<SZ_TOT / 256, 256, 0, stream>>>(
        in_proj_w, w_in, x_proj_w, w_xp, dt_proj_w, w_dt,
        out_proj_w, w_out, mlp_w1, w_m1, mlp_w2, w_m2);

    // LN1
    ln_bf16_kernel<<<NTOK, 256, 0, stream>>>(x, ln1_g, ln1_b, xn_bf);

    // in_proj: xz[4096,2048] = xn @ W^T
    gemm128_kernel<0,128><<<dim3(NTOK/128, DINNER/128), 256, 0, stream>>>(
        xn_bf, DIMD, w_in, DIMD, DINNER, nullptr, nullptr, xz, nullptr);

    // depthwise conv + silu
    conv_silu_kernel<<<dim3(HALF/256, NTOK), 256, 0, stream>>>(
        xz, conv_x_w, conv_x_b, conv_z_w, conv_z_b, u_f, u_bf, ycat);

    // x_proj: [4096,96] = u @ W^T  (writes f32 + bf16)
    gemm_small_kernel<<<dim3(NTOK/16, 96/16), 64, 0, stream>>>(
        u_bf, HALF, w_xp, HALF, 96, x_dbl, xdbl_bf);

    // dt_proj: delta = softplus(dt @ W^T + b)  (lda=96, K=64)
    gemm128_kernel<1,64><<<dim3(NTOK/128, HALF/64), 256, 0, stream>>>(
        xdbl_bf, 96, w_dt, DTRANK, HALF, dt_proj_b, nullptr, delta, nullptr);

    // chunk-parallel scan
    scan_p1_kernel<<<(BSZ*NCH*HALF*DSTATE)/256, 256, 0, stream>>>(
        delta, u_f, x_dbl, A_log, hfin, dsum);
    scan_p2_kernel<<<(BSZ*HALF*DSTATE)/256, 256, 0, stream>>>(
        A_log, dsum, hfin, hin);
    scan_p3_kernel<<<(BSZ*NCH*HALF*DSTATE)/256, 256, 0, stream>>>(
        delta, u_f, x_dbl, A_log, Dp, hin, ycat);

    // out_proj + residual: x2 = x + ycat @ W^T  (TN=64: 512 blocks)
    gemm128_kernel<3,64><<<dim3(NTOK/128, DIMD/64), 256, 0, stream>>>(
        ycat, DINNER, w_out, DINNER, DIMD, nullptr, x, x2, nullptr);

    // LN2
    ln_bf16_kernel<<<NTOK, 256, 0, stream>>>(x2, ln2_g, ln2_b, ln2_bf);

    // MLP1: gelu(ln2 @ W1^T + b1) -> bf16
    gemm128_kernel<2,128><<<dim3(NTOK/128, MLPD/128), 256, 0, stream>>>(
        ln2_bf, DIMD, w_m1, DIMD, MLPD, mlp_b1, nullptr, nullptr, mlp_h);

    // MLP2 + residual: out = x2 + mlp_h @ W2^T + b2  (TN=64: 512 blocks)
    gemm128_kernel<4,64><<<dim3(NTOK/128, DIMD/64), 256, 0, stream>>>(
        mlp_h, MLPD, w_m2, MLPD, DIMD, mlp_b2, x2, out, nullptr);
}

// Round 5
// 491.581 us; speedup vs baseline: 4.6341x; 1.0937x over previous
//
#include <hip/hip_runtime.h>
#include <math.h>

#define DIMD    1024
#define MLPD    4096
#define DSTATE  16
#define DCONV   4
#define HALF    1024
#define DINNER  2048
#define DTRANK  64
#define BSZ     2
#define SEQ     2048
#define NTOK    (BSZ*SEQ)   // 4096
#define NCH     64
#define CL      (SEQ/NCH)   // 32

typedef short bf16x8 __attribute__((ext_vector_type(8)));
typedef float f32x4  __attribute__((ext_vector_type(4)));
typedef unsigned short u16;
typedef unsigned int   u32;

__device__ __forceinline__ u16 f2bf(float x) {
    union { float f; unsigned int u; } v; v.f = x;
    unsigned int r = (v.u + 0x7FFFu + ((v.u >> 16) & 1u)) >> 16;
    return (u16)r;
}
__device__ __forceinline__ float bf2f(u16 x) {
    union { unsigned int u; float f; } v; v.u = ((unsigned int)x) << 16;
    return v.f;
}

// ---------------- fused weight f32 -> bf16 convert (6 segments) ----------
#define SZ_WIN  (DINNER*DIMD)
#define SZ_WXP  (96*HALF)
#define SZ_WDT  (HALF*DTRANK)
#define SZ_WOUT (DIMD*DINNER)
#define SZ_WM1  (MLPD*DIMD)
#define SZ_WM2  (DIMD*MLPD)
#define SZ_TOT  (SZ_WIN+SZ_WXP+SZ_WDT+SZ_WOUT+SZ_WM1+SZ_WM2)

__global__ __launch_bounds__(256) void cvt6_kernel(
        const float* __restrict__ s0, u16* __restrict__ d0,
        const float* __restrict__ s1, u16* __restrict__ d1,
        const float* __restrict__ s2, u16* __restrict__ d2,
        const float* __restrict__ s3, u16* __restrict__ d3,
        const float* __restrict__ s4, u16* __restrict__ d4,
        const float* __restrict__ s5, u16* __restrict__ d5) {
    int i = blockIdx.x * 256 + threadIdx.x;
    if (i < SZ_WIN)  { d0[i] = f2bf(s0[i]); return; }  i -= SZ_WIN;
    if (i < SZ_WXP)  { d1[i] = f2bf(s1[i]); return; }  i -= SZ_WXP;
    if (i < SZ_WDT)  { d2[i] = f2bf(s2[i]); return; }  i -= SZ_WDT;
    if (i < SZ_WOUT) { d3[i] = f2bf(s3[i]); return; }  i -= SZ_WOUT;
    if (i < SZ_WM1)  { d4[i] = f2bf(s4[i]); return; }  i -= SZ_WM1;
    d5[i] = f2bf(s5[i]);
}

// ---------------- LayerNorm (row of 1024) -> bf16 ----------------
__global__ __launch_bounds__(256) void ln_bf16_kernel(
        const float* __restrict__ x, const float* __restrict__ g,
        const float* __restrict__ b, u16* __restrict__ out) {
    __shared__ float sm[4];
    int row = blockIdx.x;
    int t = threadIdx.x;
    const float4* xr = (const float4*)(x + (size_t)row * DIMD);
    float4 v = xr[t];
    float s = v.x + v.y + v.z + v.w;
    for (int off = 32; off > 0; off >>= 1) s += __shfl_down(s, off, 64);
    if ((t & 63) == 0) sm[t >> 6] = s;
    __syncthreads();
    float mu = (sm[0] + sm[1] + sm[2] + sm[3]) * (1.0f / DIMD);
    float dx = v.x - mu, dy = v.y - mu, dz = v.z - mu, dw = v.w - mu;
    float ss = dx*dx + dy*dy + dz*dz + dw*dw;
    for (int off = 32; off > 0; off >>= 1) ss += __shfl_down(ss, off, 64);
    __syncthreads();
    if ((t & 63) == 0) sm[t >> 6] = ss;
    __syncthreads();
    float var = (sm[0] + sm[1] + sm[2] + sm[3]) * (1.0f / DIMD);
    float rs = rsqrtf(var + 1e-5f);
    float4 gv = ((const float4*)g)[t];
    float4 bv = ((const float4*)b)[t];
    u16* o = out + (size_t)row * DIMD + t * 4;
    o[0] = f2bf(dx * rs * gv.x + bv.x);
    o[1] = f2bf(dy * rs * gv.y + bv.y);
    o[2] = f2bf(dz * rs * gv.z + bv.z);
    o[3] = f2bf(dw * rs * gv.w + bv.w);
}

// ---------------- small GEMM (one wave, 16x16 tile): x_proj only ---------
__global__ __launch_bounds__(64) void gemm_small_kernel(
        const u16* __restrict__ A, int lda,
        const u16* __restrict__ W, int K, int N,
        float* __restrict__ Cf, u16* __restrict__ Cb) {
    int m0 = blockIdx.x * 16;
    int n0 = blockIdx.y * 16;
    int lane = threadIdx.x;
    int r = lane & 15, quad = lane >> 4;
    f32x4 acc = {0.f, 0.f, 0.f, 0.f};
    const u16* ap = A + (size_t)(m0 + r) * lda + quad * 8;
    const u16* wp = W + (size_t)(n0 + r) * K   + quad * 8;
    for (int k = 0; k < K; k += 32) {
        bf16x8 av = *(const bf16x8*)(ap + k);
        bf16x8 bv = *(const bf16x8*)(wp + k);
        acc = __builtin_amdgcn_mfma_f32_16x16x32_bf16(av, bv, acc, 0, 0, 0);
    }
    int col = n0 + r;
    #pragma unroll
    for (int i = 0; i < 4; ++i) {
        int row = m0 + quad * 4 + i;
        size_t idx = (size_t)row * N + col;
        Cf[idx] = acc[i];
        Cb[idx] = f2bf(acc[i]);
    }
}

// ---------------- big GEMM: 128xTN tile, BK=32, dbuf LDS, XOR swizzle ----
// EPI: 0 f32 | 1 bias+softplus f32 | 2 bias+gelu bf16 | 3 +resid f32
//      4 bias+resid f32 | 5 plain bf16
template<int EPI, int TN>
__global__ __launch_bounds__(256) void gemm128_kernel(
        const u16* __restrict__ A, int lda, const u16* __restrict__ W,
        int K, int N,
        const float* __restrict__ bias, const float* __restrict__ resid,
        float* __restrict__ Cf, u16* __restrict__ Cb) {
    constexpr int NF = TN / 32;
    __shared__ u16 As[2][128 * 32];
    __shared__ u16 Bs[2][TN * 32];
    const int t = threadIdx.x;
    const int w = t >> 6;
    const int lane = t & 63;
    const int r = lane & 15, quad = lane >> 4;
    const int wm = w & 1, wn = w >> 1;
    const int m0 = blockIdx.x * 128;
    const int n0 = blockIdx.y * TN;

    f32x4 acc[4][NF];
    #pragma unroll
    for (int mi = 0; mi < 4; ++mi)
        #pragma unroll
        for (int ni = 0; ni < NF; ++ni)
            acc[mi][ni] = (f32x4){0.f, 0.f, 0.f, 0.f};

    auto stage = [&](int buf, int k0) {
        #pragma unroll
        for (int i = 0; i < 2; ++i) {
            int c = (i * 4 + w) * 64 + lane;
            int row = c >> 2;
            int q = (c & 3) ^ ((row >> 1) & 3);
            const u16* ga = A + (size_t)(m0 + row) * lda + k0 + q * 8;
            __builtin_amdgcn_global_load_lds(
                (const __attribute__((address_space(1))) u32*)ga,
                (__attribute__((address_space(3))) u32*)(As[buf] + (i * 4 + w) * 512),
                16, 0, 0);
        }
        #pragma unroll
        for (int i = 0; i < NF / 2; ++i) {
            int c = (i * 4 + w) * 64 + lane;
            int row = c >> 2;
            int q = (c & 3) ^ ((row >> 1) & 3);
            const u16* gb = W + (size_t)(n0 + row) * K + k0 + q * 8;
            __builtin_amdgcn_global_load_lds(
                (const __attribute__((address_space(1))) u32*)gb,
                (__attribute__((address_space(3))) u32*)(Bs[buf] + (i * 4 + w) * 512),
                16, 0, 0);
        }
    };

    stage(0, 0);
    int cur = 0;
    for (int k0 = 0; k0 < K; k0 += 32, cur ^= 1) {
        __syncthreads();
        if (k0 + 32 < K) stage(cur ^ 1, k0 + 32);
        const int qs = quad ^ ((r >> 1) & 3);
        bf16x8 af[4], bfr[NF];
        #pragma unroll
        for (int mi = 0; mi < 4; ++mi) {
            int row = wm * 64 + mi * 16 + r;
            af[mi] = *(const bf16x8*)&As[cur][row * 32 + qs * 8];
        }
        #pragma unroll
        for (int ni = 0; ni < NF; ++ni) {
            int row = wn * (TN / 2) + ni * 16 + r;
            bfr[ni] = *(const bf16x8*)&Bs[cur][row * 32 + qs * 8];
        }
        #pragma unroll
        for (int mi = 0; mi < 4; ++mi)
            #pragma unroll
            for (int ni = 0; ni < NF; ++ni)
                acc[mi][ni] = __builtin_amdgcn_mfma_f32_16x16x32_bf16(
                    af[mi], bfr[ni], acc[mi][ni], 0, 0, 0);
    }
    #pragma unroll
    for (int mi = 0; mi < 4; ++mi) {
        #pragma unroll
        for (int i = 0; i < 4; ++i) {
            int row = m0 + wm * 64 + mi * 16 + quad * 4 + i;
            #pragma unroll
            for (int ni = 0; ni < NF; ++ni) {
                int col = n0 + wn * (TN / 2) + ni * 16 + r;
                size_t idx = (size_t)row * N + col;
                float v = acc[mi][ni][i];
                if (EPI == 1) { v += bias[col]; v = (v > 20.f) ? v : log1pf(expf(v)); }
                if (EPI == 2) { v += bias[col]; v = 0.5f * v * (1.0f + erff(v * 0.70710678118654752f)); }
                if (EPI == 3) { v += resid[idx]; }
                if (EPI == 4) { v += bias[col] + resid[idx]; }
                if (EPI == 2 || EPI == 5) Cb[idx] = f2bf(v);
                else                      Cf[idx] = v;
            }
        }
    }
}

// ---------------- depthwise conv(K=4, pad 1/2) + SiLU (bf16 in) ----------
__global__ __launch_bounds__(256) void conv_silu_kernel(
        const u16* __restrict__ xz,
        const float* __restrict__ wx, const float* __restrict__ bx,
        const float* __restrict__ wz, const float* __restrict__ bz,
        u16* __restrict__ u_bf, u16* __restrict__ ycat) {
    int c  = blockIdx.x * 256 + threadIdx.x;   // 0..1023
    int bl = blockIdx.y;                       // 0..B*L-1
    int l  = bl & (SEQ - 1);
    float accx = bx[c], accz = bz[c];
    #pragma unroll
    for (int k = 0; k < DCONV; ++k) {
        int lp = l + k - 1;
        if (lp >= 0 && lp < SEQ) {
            const u16* rowp = xz + (size_t)(bl + (lp - l)) * DINNER;
            accx += bf2f(rowp[c])        * wx[c * DCONV + k];
            accz += bf2f(rowp[HALF + c]) * wz[c * DCONV + k];
        }
    }
    float sx = accx * __fdividef(1.f, 1.f + __expf(-accx));
    float sz = accz * __fdividef(1.f, 1.f + __expf(-accz));
    u_bf[(size_t)bl * HALF + c] = f2bf(sx);
    ycat[(size_t)bl * DINNER + HALF + c] = f2bf(sz);
}

// ---------------- chunk-parallel selective scan (thread per chain) -------
// chain t = (b*NCH + ch)*HALF + d ; h[16], Ac[16] in registers.
__global__ __launch_bounds__(256) void scan_p1_kernel(
        const float* __restrict__ delta, const u16* __restrict__ u_bf,
        const float* __restrict__ x_dbl, const float* __restrict__ A_log,
        float* __restrict__ hfin, float* __restrict__ dsum) {
    int t  = blockIdx.x * 256 + threadIdx.x;
    int d  = t & (HALF - 1);
    int ch = (t >> 10) & (NCH - 1);
    int b  = t >> 16;
    float Ac[16], h[16];
    #pragma unroll
    for (int i = 0; i < 4; ++i) {
        float4 a = *(const float4*)&A_log[d * DSTATE + i * 4];
        Ac[4*i+0] = -__expf(a.x); Ac[4*i+1] = -__expf(a.y);
        Ac[4*i+2] = -__expf(a.z); Ac[4*i+3] = -__expf(a.w);
        h[4*i+0] = 0.f; h[4*i+1] = 0.f; h[4*i+2] = 0.f; h[4*i+3] = 0.f;
    }
    int l0 = b * SEQ + ch * CL;
    size_t off = (size_t)l0 * HALF + d;
    const float* xrow = x_dbl + (size_t)l0 * 96;
    float ds = 0.f;
    #pragma unroll 4
    for (int l = 0; l < CL; ++l) {
        float dl = delta[off];
        float uv = bf2f(u_bf[off]);
        off += HALF;
        float4 B0 = *(const float4*)(xrow + 64);
        float4 B1 = *(const float4*)(xrow + 68);
        float4 B2 = *(const float4*)(xrow + 72);
        float4 B3 = *(const float4*)(xrow + 76);
        xrow += 96;
        float dBu = dl * uv;
        ds += dl;
        float Bv[16] = {B0.x,B0.y,B0.z,B0.w, B1.x,B1.y,B1.z,B1.w,
                        B2.x,B2.y,B2.z,B2.w, B3.x,B3.y,B3.z,B3.w};
        #pragma unroll
        for (int n = 0; n < 16; ++n)
            h[n] = __expf(dl * Ac[n]) * h[n] + dBu * Bv[n];
    }
    float4* hf = (float4*)&hfin[(size_t)t * 16];
    #pragma unroll
    for (int i = 0; i < 4; ++i)
        hf[i] = (float4){h[4*i+0], h[4*i+1], h[4*i+2], h[4*i+3]};
    dsum[t] = ds;
}

__global__ __launch_bounds__(256) void scan_p2_kernel(
        const float* __restrict__ A_log, const float* __restrict__ dsum,
        const float* __restrict__ hfin, float* __restrict__ hin) {
    int t = blockIdx.x * 256 + threadIdx.x;   // 0..B*HALF*16-1
    int n = t & 15;
    int d = (t >> 4) & (HALF - 1);
    int b = t >> 14;
    float Ac = -__expf(A_log[d * DSTATE + n]);
    float h = 0.f;
    for (int ch = 0; ch < NCH; ++ch) {
        size_t chain = ((size_t)(b * NCH + ch) * HALF) + d;
        hin[chain * 16 + n] = h;
        float ds = dsum[chain];
        h = __expf(Ac * ds) * h + hfin[chain * 16 + n];
    }
}

__global__ __launch_bounds__(256) void scan_p3_kernel(
        const float* __restrict__ delta, const u16* __restrict__ u_bf,
        const float* __restrict__ x_dbl, const float* __restrict__ A_log,
        const float* __restrict__ Dp, const float* __restrict__ hin,
        u16* __restrict__ ycat) {
    int t  = blockIdx.x * 256 + threadIdx.x;
    int d  = t & (HALF - 1);
    int ch = (t >> 10) & (NCH - 1);
    int b  = t >> 16;
    float Ac[16], h[16];
    #pragma unroll
    for (int i = 0; i < 4; ++i) {
        float4 a  = *(const float4*)&A_log[d * DSTATE + i * 4];
        float4 hv = *(const float4*)&hin[(size_t)t * 16 + i * 4];
        Ac[4*i+0] = -__expf(a.x); Ac[4*i+1] = -__expf(a.y);
        Ac[4*i+2] = -__expf(a.z); Ac[4*i+3] = -__expf(a.w);
        h[4*i+0] = hv.x; h[4*i+1] = hv.y; h[4*i+2] = hv.z; h[4*i+3] = hv.w;
    }
    float Dv = Dp[d];
    int l0 = b * SEQ + ch * CL;
    size_t off = (size_t)l0 * HALF + d;
    const float* xrow = x_dbl + (size_t)l0 * 96;
    u16* yp = ycat + (size_t)l0 * DINNER + d;
    #pragma unroll 4
    for (int l = 0; l < CL; ++l) {
        float dl = delta[off];
        float uv = bf2f(u_bf[off]);
        off += HALF;
        float4 B0 = *(const float4*)(xrow + 64);
        float4 B1 = *(const float4*)(xrow + 68);
        float4 B2 = *(const float4*)(xrow + 72);
        float4 B3 = *(const float4*)(xrow + 76);
        float4 C0 = *(const float4*)(xrow + 80);
        float4 C1 = *(const float4*)(xrow + 84);
        float4 C2 = *(const float4*)(xrow + 88);
        float4 C3 = *(const float4*)(xrow + 92);
        xrow += 96;
        float dBu = dl * uv;
        float Bv[16] = {B0.x,B0.y,B0.z,B0.w, B1.x,B1.y,B1.z,B1.w,
                        B2.x,B2.y,B2.z,B2.w, B3.x,B3.y,B3.z,B3.w};
        float Cv[16] = {C0.x,C0.y,C0.z,C0.w, C1.x,C1.y,C1.z,C1.w,
                        C2.x,C2.y,C2.z,C2.w, C3.x,C3.y,C3.z,C3.w};
        float y = uv * Dv;
        #pragma unroll
        for (int n = 0; n < 16; ++n) {
            h[n] = __expf(dl * Ac[n]) * h[n] + dBu * Bv[n];
            y += h[n] * Cv[n];
        }
        *yp = f2bf(y);
        yp += DINNER;
    }
}

// ---------------- host-side orchestration ----------------
extern "C" void kernel_launch(void* const* d_in, const int* in_sizes, int n_in,
                              void* d_out, int out_size, void* d_ws, size_t ws_size,
                              hipStream_t stream) {
    const float* x         = (const float*)d_in[0];
    const float* ln1_g     = (const float*)d_in[1];
    const float* ln1_b     = (const float*)d_in[2];
    const float* in_proj_w = (const float*)d_in[3];
    const float* conv_x_w  = (const float*)d_in[4];
    const float* conv_x_b  = (const float*)d_in[5];
    const float* conv_z_w  = (const float*)d_in[6];
    const float* conv_z_b  = (const float*)d_in[7];
    const float* x_proj_w  = (const float*)d_in[8];
    const float* dt_proj_w = (const float*)d_in[9];
    const float* dt_proj_b = (const float*)d_in[10];
    const float* A_log     = (const float*)d_in[11];
    const float* Dp        = (const float*)d_in[12];
    const float* out_proj_w= (const float*)d_in[13];
    const float* ln2_g     = (const float*)d_in[14];
    const float* ln2_b     = (const float*)d_in[15];
    const float* mlp_w1    = (const float*)d_in[16];
    const float* mlp_b1    = (const float*)d_in[17];
    const float* mlp_w2    = (const float*)d_in[18];
    const float* mlp_b2    = (const float*)d_in[19];
    float* out = (float*)d_out;

    char* p = (char*)d_ws;
    auto alloc = [&](size_t bytes) {
        char* r = p; p += (bytes + 255) & ~(size_t)255; return r;
    };
    u16*   w_in   = (u16*)  alloc((size_t)DINNER * DIMD * 2);
    u16*   w_xp   = (u16*)  alloc((size_t)96 * HALF * 2);
    u16*   w_dt   = (u16*)  alloc((size_t)HALF * DTRANK * 2);
    u16*   w_out  = (u16*)  alloc((size_t)DIMD * DINNER * 2);
    u16*   w_m1   = (u16*)  alloc((size_t)MLPD * DIMD * 2);
    u16*   w_m2   = (u16*)  alloc((size_t)DIMD * MLPD * 2);
    u16*   xn_bf  = (u16*)  alloc((size_t)NTOK * DIMD * 2);
    u16*   xz_bf  = (u16*)  alloc((size_t)NTOK * DINNER * 2);  // 16 MB
    u16*   u_bf   = (u16*)  alloc((size_t)NTOK * HALF * 2);
    u16*   ycat   = (u16*)  alloc((size_t)NTOK * DINNER * 2);
    float* x_dbl  = (float*)alloc((size_t)NTOK * 96 * 4);
    u16*   xdbl_bf= (u16*)  alloc((size_t)NTOK * 96 * 2);
    float* delta  = (float*)alloc((size_t)NTOK * HALF * 4);
    float* x2     = (float*)alloc((size_t)NTOK * DIMD * 4);
    u16*   ln2_bf = (u16*)  alloc((size_t)NTOK * DIMD * 2);
    u16*   mlp_h  = (u16*)  alloc((size_t)NTOK * MLPD * 2);   // 32 MB
    // scan scratch aliases mlp_h (dead until mlp1, which runs after scan):
    float* hfin = (float*)mlp_h;                              // 8 MB
    float* hin  = hfin + (size_t)BSZ * NCH * HALF * DSTATE;   // 8 MB
    float* dsum = hin  + (size_t)BSZ * NCH * HALF * DSTATE;   // 512 KB

    cvt6_kernel<<<SZ_TOT / 256, 256, 0, stream>>>(
        in_proj_w, w_in, x_proj_w, w_xp, dt_proj_w, w_dt,
        out_proj_w, w_out, mlp_w1, w_m1, mlp_w2, w_m2);

    // LN1
    ln_bf16_kernel<<<NTOK, 256, 0, stream>>>(x, ln1_g, ln1_b, xn_bf);

    // in_proj: xz_bf[4096,2048] = xn @ W^T (bf16 out)
    gemm128_kernel<5,128><<<dim3(NTOK/128, DINNER/128), 256, 0, stream>>>(
        xn_bf, DIMD, w_in, DIMD, DINNER, nullptr, nullptr, nullptr, xz_bf);

    // depthwise conv + silu (bf16 in)
    conv_silu_kernel<<<dim3(HALF/256, NTOK), 256, 0, stream>>>(
        xz_bf, conv_x_w, conv_x_b, conv_z_w, conv_z_b, u_bf, ycat);

    // x_proj: [4096,96] = u @ W^T  (f32 + bf16 out)
    gemm_small_kernel<<<dim3(NTOK/16, 96/16), 64, 0, stream>>>(
        u_bf, HALF, w_xp, HALF, 96, x_dbl, xdbl_bf);

    // dt_proj: delta = softplus(dt @ W^T + b)
    gemm128_kernel<1,64><<<dim3(NTOK/128, HALF/64), 256, 0, stream>>>(
        xdbl_bf, 96, w_dt, DTRANK, HALF, dt_proj_b, nullptr, delta, nullptr);

    // chunk-parallel scan (thread per chain, n in registers)
    scan_p1_kernel<<<(BSZ*NCH*HALF)/256, 256, 0, stream>>>(
        delta, u_bf, x_dbl, A_log, hfin, dsum);
    scan_p2_kernel<<<(BSZ*HALF*DSTATE)/256, 256, 0, stream>>>(
        A_log, dsum, hfin, hin);
    scan_p3_kernel<<<(BSZ*NCH*HALF)/256, 256, 0, stream>>>(
        delta, u_bf, x_dbl, A_log, Dp, hin, ycat);

    // out_proj + residual: x2 = x + ycat @ W^T
    gemm128_kernel<3,64><<<dim3(NTOK/128, DIMD/64), 256, 0, stream>>>(
        ycat, DINNER, w_out, DINNER, DIMD, nullptr, x, x2, nullptr);

    // LN2
    ln_bf16_kernel<<<NTOK, 256, 0, stream>>>(x2, ln2_g, ln2_b, ln2_bf);

    // MLP1: gelu(ln2 @ W1^T + b1) -> bf16 (overwrites scan scratch - ok)
    gemm128_kernel<2,128><<<dim3(NTOK/128, MLPD/128), 256, 0, stream>>>(
        ln2_bf, DIMD, w_m1, DIMD, MLPD, mlp_b1, nullptr, nullptr, mlp_h);

    // MLP2 + residual: out = x2 + mlp_h @ W2^T + b2
    gemm128_kernel<4,64><<<dim3(NTOK/128, DIMD/64), 256, 0, stream>>>(
        mlp_h, MLPD, w_m2, MLPD, DIMD, mlp_b2, x2, out, nullptr);
}

// Round 6
// 480.928 us; speedup vs baseline: 4.7368x; 1.0222x over previous
//
#include <hip/hip_runtime.h>
#include <math.h>

#define DIMD    1024
#define MLPD    4096
#define DSTATE  16
#define DCONV   4
#define HALF    1024
#define DINNER  2048
#define DTRANK  64
#define BSZ     2
#define SEQ     2048
#define NTOK    (BSZ*SEQ)   // 4096
#define NCH     64
#define CL      (SEQ/NCH)   // 32

typedef short bf16x8 __attribute__((ext_vector_type(8)));
typedef float f32x4  __attribute__((ext_vector_type(4)));
typedef unsigned short u16;
typedef unsigned int   u32;

__device__ __forceinline__ u16 f2bf(float x) {
    union { float f; unsigned int u; } v; v.f = x;
    unsigned int r = (v.u + 0x7FFFu + ((v.u >> 16) & 1u)) >> 16;
    return (u16)r;
}
__device__ __forceinline__ float bf2f(u16 x) {
    union { unsigned int u; float f; } v; v.u = ((unsigned int)x) << 16;
    return v.f;
}

// ---------------- fused weight f32 -> bf16 convert (6 segments) ----------
#define SZ_WIN  (DINNER*DIMD)
#define SZ_WXP  (96*HALF)
#define SZ_WDT  (HALF*DTRANK)
#define SZ_WOUT (DIMD*DINNER)
#define SZ_WM1  (MLPD*DIMD)
#define SZ_WM2  (DIMD*MLPD)
#define SZ_TOT  (SZ_WIN+SZ_WXP+SZ_WDT+SZ_WOUT+SZ_WM1+SZ_WM2)

__global__ __launch_bounds__(256) void cvt6_kernel(
        const float* __restrict__ s0, u16* __restrict__ d0,
        const float* __restrict__ s1, u16* __restrict__ d1,
        const float* __restrict__ s2, u16* __restrict__ d2,
        const float* __restrict__ s3, u16* __restrict__ d3,
        const float* __restrict__ s4, u16* __restrict__ d4,
        const float* __restrict__ s5, u16* __restrict__ d5) {
    int i = blockIdx.x * 256 + threadIdx.x;
    if (i < SZ_WIN)  { d0[i] = f2bf(s0[i]); return; }  i -= SZ_WIN;
    if (i < SZ_WXP)  { d1[i] = f2bf(s1[i]); return; }  i -= SZ_WXP;
    if (i < SZ_WDT)  { d2[i] = f2bf(s2[i]); return; }  i -= SZ_WDT;
    if (i < SZ_WOUT) { d3[i] = f2bf(s3[i]); return; }  i -= SZ_WOUT;
    if (i < SZ_WM1)  { d4[i] = f2bf(s4[i]); return; }  i -= SZ_WM1;
    d5[i] = f2bf(s5[i]);
}

// ---------------- LayerNorm (row of 1024) -> bf16 ----------------
__global__ __launch_bounds__(256) void ln_bf16_kernel(
        const float* __restrict__ x, const float* __restrict__ g,
        const float* __restrict__ b, u16* __restrict__ out) {
    __shared__ float sm[4];
    int row = blockIdx.x;
    int t = threadIdx.x;
    const float4* xr = (const float4*)(x + (size_t)row * DIMD);
    float4 v = xr[t];
    float s = v.x + v.y + v.z + v.w;
    for (int off = 32; off > 0; off >>= 1) s += __shfl_down(s, off, 64);
    if ((t & 63) == 0) sm[t >> 6] = s;
    __syncthreads();
    float mu = (sm[0] + sm[1] + sm[2] + sm[3]) * (1.0f / DIMD);
    float dx = v.x - mu, dy = v.y - mu, dz = v.z - mu, dw = v.w - mu;
    float ss = dx*dx + dy*dy + dz*dz + dw*dw;
    for (int off = 32; off > 0; off >>= 1) ss += __shfl_down(ss, off, 64);
    __syncthreads();
    if ((t & 63) == 0) sm[t >> 6] = ss;
    __syncthreads();
    float var = (sm[0] + sm[1] + sm[2] + sm[3]) * (1.0f / DIMD);
    float rs = rsqrtf(var + 1e-5f);
    float4 gv = ((const float4*)g)[t];
    float4 bv = ((const float4*)b)[t];
    u16* o = out + (size_t)row * DIMD + t * 4;
    o[0] = f2bf(dx * rs * gv.x + bv.x);
    o[1] = f2bf(dy * rs * gv.y + bv.y);
    o[2] = f2bf(dz * rs * gv.z + bv.z);
    o[3] = f2bf(dw * rs * gv.w + bv.w);
}

// ---------------- small GEMM (one wave, 16x16 tile): x_proj only ---------
__global__ __launch_bounds__(64) void gemm_small_kernel(
        const u16* __restrict__ A, int lda,
        const u16* __restrict__ W, int K, int N,
        float* __restrict__ Cf, u16* __restrict__ Cb) {
    int m0 = blockIdx.x * 16;
    int n0 = blockIdx.y * 16;
    int lane = threadIdx.x;
    int r = lane & 15, quad = lane >> 4;
    f32x4 acc = {0.f, 0.f, 0.f, 0.f};
    const u16* ap = A + (size_t)(m0 + r) * lda + quad * 8;
    const u16* wp = W + (size_t)(n0 + r) * K   + quad * 8;
    for (int k = 0; k < K; k += 32) {
        bf16x8 av = *(const bf16x8*)(ap + k);
        bf16x8 bv = *(const bf16x8*)(wp + k);
        acc = __builtin_amdgcn_mfma_f32_16x16x32_bf16(av, bv, acc, 0, 0, 0);
    }
    int col = n0 + r;
    #pragma unroll
    for (int i = 0; i < 4; ++i) {
        int row = m0 + quad * 4 + i;
        size_t idx = (size_t)row * N + col;
        Cf[idx] = acc[i];
        Cb[idx] = f2bf(acc[i]);
    }
}

// ---------------- big GEMM: 128xTN tile, BK=32, dbuf, hoisted addrs ------
// C[M,N] = A[M,K] * W[N,K]^T, bf16 in, f32 acc. M%128, N%TN, (K/KS)%64 == 0.
// EPI: 0 f32 | 1 bias+softplus f32 | 2 bias+gelu bf16 | 3 +resid f32
//      4 bias+resid f32 | 5 plain bf16
// KS==2: blockIdx.z selects K-half; partial f32 -> Cf (z=0) / Cf2 (z=1).
template<int EPI, int TN, int KS>
__global__ __launch_bounds__(256) void gemm128_kernel(
        const u16* __restrict__ A, int lda, const u16* __restrict__ W,
        int K, int N,
        const float* __restrict__ bias, const float* __restrict__ resid,
        float* __restrict__ Cf, float* __restrict__ Cf2,
        u16* __restrict__ Cb) {
    constexpr int NF = TN / 32;
    __shared__ u16 As0[128 * 32], As1[128 * 32];
    __shared__ u16 Bs0[TN * 32],  Bs1[TN * 32];
    const int t = threadIdx.x;
    const int w = t >> 6;
    const int lane = t & 63;
    const int r = lane & 15, quad = lane >> 4;
    const int wm = w & 1, wn = w >> 1;
    const int m0 = blockIdx.x * 128;
    const int n0 = blockIdx.y * TN;
    const int Kloc = K / KS;
    const int kz = (KS == 2) ? blockIdx.z : 0;

    f32x4 acc[4][NF];
    #pragma unroll
    for (int mi = 0; mi < 4; ++mi)
        #pragma unroll
        for (int ni = 0; ni < NF; ++ni)
            acc[mi][ni] = (f32x4){0.f, 0.f, 0.f, 0.f};

    // ---- hoisted staging pointers (bumped +32 elements per stage) ----
    const u16* pa[2];
    const u16* pb[NF / 2];
    #pragma unroll
    for (int i = 0; i < 2; ++i) {
        int c = (i * 4 + w) * 64 + lane;
        int row = c >> 2;
        int q = (c & 3) ^ ((row >> 1) & 3);
        pa[i] = A + (size_t)(m0 + row) * lda + (size_t)kz * Kloc + q * 8;
    }
    #pragma unroll
    for (int i = 0; i < NF / 2; ++i) {
        int c = (i * 4 + w) * 64 + lane;
        int row = c >> 2;
        int q = (c & 3) ^ ((row >> 1) & 3);
        pb[i] = W + (size_t)(n0 + row) * K + (size_t)kz * Kloc + q * 8;
    }
    // ---- hoisted LDS read offsets ----
    const int qs = quad ^ ((r >> 1) & 3);
    int aoff[4], boff[NF];
    #pragma unroll
    for (int mi = 0; mi < 4; ++mi)
        aoff[mi] = (wm * 64 + mi * 16 + r) * 32 + qs * 8;
    #pragma unroll
    for (int ni = 0; ni < NF; ++ni)
        boff[ni] = (wn * (TN / 2) + ni * 16 + r) * 32 + qs * 8;

    auto stage = [&](u16* __restrict__ Ad, u16* __restrict__ Bd) {
        #pragma unroll
        for (int i = 0; i < 2; ++i) {
            __builtin_amdgcn_global_load_lds(
                (const __attribute__((address_space(1))) u32*)pa[i],
                (__attribute__((address_space(3))) u32*)(Ad + (i * 4 + w) * 512),
                16, 0, 0);
            pa[i] += 32;
        }
        #pragma unroll
        for (int i = 0; i < NF / 2; ++i) {
            __builtin_amdgcn_global_load_lds(
                (const __attribute__((address_space(1))) u32*)pb[i],
                (__attribute__((address_space(3))) u32*)(Bd + (i * 4 + w) * 512),
                16, 0, 0);
            pb[i] += 32;
        }
    };
    auto compute = [&](const u16* __restrict__ Ab, const u16* __restrict__ Bb) {
        bf16x8 af[4], bfr[NF];
        #pragma unroll
        for (int mi = 0; mi < 4; ++mi) af[mi] = *(const bf16x8*)(Ab + aoff[mi]);
        #pragma unroll
        for (int ni = 0; ni < NF; ++ni) bfr[ni] = *(const bf16x8*)(Bb + boff[ni]);
        #pragma unroll
        for (int mi = 0; mi < 4; ++mi)
            #pragma unroll
            for (int ni = 0; ni < NF; ++ni)
                acc[mi][ni] = __builtin_amdgcn_mfma_f32_16x16x32_bf16(
                    af[mi], bfr[ni], acc[mi][ni], 0, 0, 0);
    };

    stage(As0, Bs0);
    for (int k0 = 0; k0 < Kloc; k0 += 64) {
        __syncthreads();                          // As0/Bs0 staging visible
        if (k0 + 32 < Kloc) stage(As1, Bs1);
        compute(As0, Bs0);
        __syncthreads();                          // As1/Bs1 staging visible
        if (k0 + 64 < Kloc) stage(As0, Bs0);
        compute(As1, Bs1);
    }

    float* Cfo = (KS == 2 && kz) ? Cf2 : Cf;
    #pragma unroll
    for (int mi = 0; mi < 4; ++mi) {
        #pragma unroll
        for (int i = 0; i < 4; ++i) {
            int row = m0 + wm * 64 + mi * 16 + quad * 4 + i;
            #pragma unroll
            for (int ni = 0; ni < NF; ++ni) {
                int col = n0 + wn * (TN / 2) + ni * 16 + r;
                size_t idx = (size_t)row * N + col;
                float v = acc[mi][ni][i];
                if (EPI == 1) { v += bias[col]; v = (v > 20.f) ? v : log1pf(expf(v)); }
                if (EPI == 2) { v += bias[col]; v = 0.5f * v * (1.0f + erff(v * 0.70710678118654752f)); }
                if (EPI == 3) { v += resid[idx]; }
                if (EPI == 4) { v += bias[col] + resid[idx]; }
                if (EPI == 2 || EPI == 5) Cb[idx] = f2bf(v);
                else                      Cfo[idx] = v;
            }
        }
    }
}

// ---------------- split-K reduce: out = P0 + P1 (+bias) + resid ----------
// EPI 3: resid only | EPI 4: bias + resid. N must be 1024 (DIMD).
template<int EPI>
__global__ __launch_bounds__(256) void reduce2_kernel(
        const float* __restrict__ P0, const float* __restrict__ P1,
        const float* __restrict__ bias, const float* __restrict__ resid,
        float* __restrict__ out) {
    size_t idx = ((size_t)blockIdx.x * 256 + threadIdx.x) * 4;
    float4 a = *(const float4*)(P0 + idx);
    float4 b = *(const float4*)(P1 + idx);
    float4 rr = *(const float4*)(resid + idx);
    float4 o;
    o.x = a.x + b.x + rr.x;
    o.y = a.y + b.y + rr.y;
    o.z = a.z + b.z + rr.z;
    o.w = a.w + b.w + rr.w;
    if (EPI == 4) {
        int col = (int)(idx & (DIMD - 1));
        float4 bb = *(const float4*)(bias + col);
        o.x += bb.x; o.y += bb.y; o.z += bb.z; o.w += bb.w;
    }
    *(float4*)(out + idx) = o;
}

// ---------------- depthwise conv(K=4, pad 1/2) + SiLU (bf16 in) ----------
__global__ __launch_bounds__(256) void conv_silu_kernel(
        const u16* __restrict__ xz,
        const float* __restrict__ wx, const float* __restrict__ bx,
        const float* __restrict__ wz, const float* __restrict__ bz,
        u16* __restrict__ u_bf, u16* __restrict__ ycat) {
    int c  = blockIdx.x * 256 + threadIdx.x;   // 0..1023
    int bl = blockIdx.y;                       // 0..B*L-1
    int l  = bl & (SEQ - 1);
    float accx = bx[c], accz = bz[c];
    #pragma unroll
    for (int k = 0; k < DCONV; ++k) {
        int lp = l + k - 1;
        if (lp >= 0 && lp < SEQ) {
            const u16* rowp = xz + (size_t)(bl + (lp - l)) * DINNER;
            accx += bf2f(rowp[c])        * wx[c * DCONV + k];
            accz += bf2f(rowp[HALF + c]) * wz[c * DCONV + k];
        }
    }
    float sx = accx * __fdividef(1.f, 1.f + __expf(-accx));
    float sz = accz * __fdividef(1.f, 1.f + __expf(-accz));
    u_bf[(size_t)bl * HALF + c] = f2bf(sx);
    ycat[(size_t)bl * DINNER + HALF + c] = f2bf(sz);
}

// ---------------- chunk-parallel selective scan (thread per chain) -------
__global__ __launch_bounds__(256) void scan_p1_kernel(
        const float* __restrict__ delta, const u16* __restrict__ u_bf,
        const float* __restrict__ x_dbl, const float* __restrict__ A_log,
        float* __restrict__ hfin, float* __restrict__ dsum) {
    int t  = blockIdx.x * 256 + threadIdx.x;
    int d  = t & (HALF - 1);
    int ch = (t >> 10) & (NCH - 1);
    int b  = t >> 16;
    float Ac[16], h[16];
    #pragma unroll
    for (int i = 0; i < 4; ++i) {
        float4 a = *(const float4*)&A_log[d * DSTATE + i * 4];
        Ac[4*i+0] = -__expf(a.x); Ac[4*i+1] = -__expf(a.y);
        Ac[4*i+2] = -__expf(a.z); Ac[4*i+3] = -__expf(a.w);
        h[4*i+0] = 0.f; h[4*i+1] = 0.f; h[4*i+2] = 0.f; h[4*i+3] = 0.f;
    }
    int l0 = b * SEQ + ch * CL;
    size_t off = (size_t)l0 * HALF + d;
    const float* xrow = x_dbl + (size_t)l0 * 96;
    float ds = 0.f;
    #pragma unroll 4
    for (int l = 0; l < CL; ++l) {
        float dl = delta[off];
        float uv = bf2f(u_bf[off]);
        off += HALF;
        float4 B0 = *(const float4*)(xrow + 64);
        float4 B1 = *(const float4*)(xrow + 68);
        float4 B2 = *(const float4*)(xrow + 72);
        float4 B3 = *(const float4*)(xrow + 76);
        xrow += 96;
        float dBu = dl * uv;
        ds += dl;
        float Bv[16] = {B0.x,B0.y,B0.z,B0.w, B1.x,B1.y,B1.z,B1.w,
                        B2.x,B2.y,B2.z,B2.w, B3.x,B3.y,B3.z,B3.w};
        #pragma unroll
        for (int n = 0; n < 16; ++n)
            h[n] = __expf(dl * Ac[n]) * h[n] + dBu * Bv[n];
    }
    float4* hf = (float4*)&hfin[(size_t)t * 16];
    #pragma unroll
    for (int i = 0; i < 4; ++i)
        hf[i] = (float4){h[4*i+0], h[4*i+1], h[4*i+2], h[4*i+3]};
    dsum[t] = ds;
}

__global__ __launch_bounds__(256) void scan_p2_kernel(
        const float* __restrict__ A_log, const float* __restrict__ dsum,
        const float* __restrict__ hfin, float* __restrict__ hin) {
    int t = blockIdx.x * 256 + threadIdx.x;   // 0..B*HALF*16-1
    int n = t & 15;
    int d = (t >> 4) & (HALF - 1);
    int b = t >> 14;
    float Ac = -__expf(A_log[d * DSTATE + n]);
    float h = 0.f;
    for (int ch = 0; ch < NCH; ++ch) {
        size_t chain = ((size_t)(b * NCH + ch) * HALF) + d;
        hin[chain * 16 + n] = h;
        float ds = dsum[chain];
        h = __expf(Ac * ds) * h + hfin[chain * 16 + n];
    }
}

__global__ __launch_bounds__(256) void scan_p3_kernel(
        const float* __restrict__ delta, const u16* __restrict__ u_bf,
        const float* __restrict__ x_dbl, const float* __restrict__ A_log,
        const float* __restrict__ Dp, const float* __restrict__ hin,
        u16* __restrict__ ycat) {
    int t  = blockIdx.x * 256 + threadIdx.x;
    int d  = t & (HALF - 1);
    int ch = (t >> 10) & (NCH - 1);
    int b  = t >> 16;
    float Ac[16], h[16];
    #pragma unroll
    for (int i = 0; i < 4; ++i) {
        float4 a  = *(const float4*)&A_log[d * DSTATE + i * 4];
        float4 hv = *(const float4*)&hin[(size_t)t * 16 + i * 4];
        Ac[4*i+0] = -__expf(a.x); Ac[4*i+1] = -__expf(a.y);
        Ac[4*i+2] = -__expf(a.z); Ac[4*i+3] = -__expf(a.w);
        h[4*i+0] = hv.x; h[4*i+1] = hv.y; h[4*i+2] = hv.z; h[4*i+3] = hv.w;
    }
    float Dv = Dp[d];
    int l0 = b * SEQ + ch * CL;
    size_t off = (size_t)l0 * HALF + d;
    const float* xrow = x_dbl + (size_t)l0 * 96;
    u16* yp = ycat + (size_t)l0 * DINNER + d;
    #pragma unroll 4
    for (int l = 0; l < CL; ++l) {
        float dl = delta[off];
        float uv = bf2f(u_bf[off]);
        off += HALF;
        float4 B0 = *(const float4*)(xrow + 64);
        float4 B1 = *(const float4*)(xrow + 68);
        float4 B2 = *(const float4*)(xrow + 72);
        float4 B3 = *(const float4*)(xrow + 76);
        float4 C0 = *(const float4*)(xrow + 80);
        float4 C1 = *(const float4*)(xrow + 84);
        float4 C2 = *(const float4*)(xrow + 88);
        float4 C3 = *(const float4*)(xrow + 92);
        xrow += 96;
        float dBu = dl * uv;
        float Bv[16] = {B0.x,B0.y,B0.z,B0.w, B1.x,B1.y,B1.z,B1.w,
                        B2.x,B2.y,B2.z,B2.w, B3.x,B3.y,B3.z,B3.w};
        float Cv[16] = {C0.x,C0.y,C0.z,C0.w, C1.x,C1.y,C1.z,C1.w,
                        C2.x,C2.y,C2.z,C2.w, C3.x,C3.y,C3.z,C3.w};
        float y = uv * Dv;
        #pragma unroll
        for (int n = 0; n < 16; ++n) {
            h[n] = __expf(dl * Ac[n]) * h[n] + dBu * Bv[n];
            y += h[n] * Cv[n];
        }
        *yp = f2bf(y);
        yp += DINNER;
    }
}

// ---------------- host-side orchestration ----------------
extern "C" void kernel_launch(void* const* d_in, const int* in_sizes, int n_in,
                              void* d_out, int out_size, void* d_ws, size_t ws_size,
                              hipStream_t stream) {
    const float* x         = (const float*)d_in[0];
    const float* ln1_g     = (const float*)d_in[1];
    const float* ln1_b     = (const float*)d_in[2];
    const float* in_proj_w = (const float*)d_in[3];
    const float* conv_x_w  = (const float*)d_in[4];
    const float* conv_x_b  = (const float*)d_in[5];
    const float* conv_z_w  = (const float*)d_in[6];
    const float* conv_z_b  = (const float*)d_in[7];
    const float* x_proj_w  = (const float*)d_in[8];
    const float* dt_proj_w = (const float*)d_in[9];
    const float* dt_proj_b = (const float*)d_in[10];
    const float* A_log     = (const float*)d_in[11];
    const float* Dp        = (const float*)d_in[12];
    const float* out_proj_w= (const float*)d_in[13];
    const float* ln2_g     = (const float*)d_in[14];
    const float* ln2_b     = (const float*)d_in[15];
    const float* mlp_w1    = (const float*)d_in[16];
    const float* mlp_b1    = (const float*)d_in[17];
    const float* mlp_w2    = (const float*)d_in[18];
    const float* mlp_b2    = (const float*)d_in[19];
    float* out = (float*)d_out;

    char* p = (char*)d_ws;
    auto alloc = [&](size_t bytes) {
        char* r = p; p += (bytes + 255) & ~(size_t)255; return r;
    };
    u16*   w_in   = (u16*)  alloc((size_t)DINNER * DIMD * 2);
    u16*   w_xp   = (u16*)  alloc((size_t)96 * HALF * 2);
    u16*   w_dt   = (u16*)  alloc((size_t)HALF * DTRANK * 2);
    u16*   w_out  = (u16*)  alloc((size_t)DIMD * DINNER * 2);
    u16*   w_m1   = (u16*)  alloc((size_t)MLPD * DIMD * 2);
    u16*   w_m2   = (u16*)  alloc((size_t)DIMD * MLPD * 2);
    u16*   xn_bf  = (u16*)  alloc((size_t)NTOK * DIMD * 2);
    u16*   xz_bf  = (u16*)  alloc((size_t)NTOK * DINNER * 2);  // 16 MB
    u16*   u_bf   = (u16*)  alloc((size_t)NTOK * HALF * 2);
    u16*   ycat   = (u16*)  alloc((size_t)NTOK * DINNER * 2);
    float* x_dbl  = (float*)alloc((size_t)NTOK * 96 * 4);
    u16*   xdbl_bf= (u16*)  alloc((size_t)NTOK * 96 * 2);
    float* delta  = (float*)alloc((size_t)NTOK * HALF * 4);    // 16 MB
    float* x2     = (float*)alloc((size_t)NTOK * DIMD * 4);
    u16*   ln2_bf = (u16*)  alloc((size_t)NTOK * DIMD * 2);
    u16*   mlp_h  = (u16*)  alloc((size_t)NTOK * MLPD * 2);    // 32 MB
    // scan scratch aliases mlp_h (dead until mlp1):
    float* hfin = (float*)mlp_h;
    float* hin  = hfin + (size_t)BSZ * NCH * HALF * DSTATE;
    float* dsum = hin  + (size_t)BSZ * NCH * HALF * DSTATE;
    // split-K partials alias delta (dead after scan) and xz_bf (dead after conv):
    float* P0 = delta;
    float* P1 = (float*)xz_bf;

    cvt6_kernel<<<SZ_TOT / 256, 256, 0, stream>>>(
        in_proj_w, w_in, x_proj_w, w_xp, dt_proj_w, w_dt,
        out_proj_w, w_out, mlp_w1, w_m1, mlp_w2, w_m2);

    // LN1
    ln_bf16_kernel<<<NTOK, 256, 0, stream>>>(x, ln1_g, ln1_b, xn_bf);

    // in_proj: xz_bf[4096,2048] = xn @ W^T (bf16 out)
    gemm128_kernel<5,128,1><<<dim3(NTOK/128, DINNER/128), 256, 0, stream>>>(
        xn_bf, DIMD, w_in, DIMD, DINNER, nullptr, nullptr, nullptr, nullptr, xz_bf);

    // depthwise conv + silu (bf16 in)
    conv_silu_kernel<<<dim3(HALF/256, NTOK), 256, 0, stream>>>(
        xz_bf, conv_x_w, conv_x_b, conv_z_w, conv_z_b, u_bf, ycat);

    // x_proj: [4096,96] = u @ W^T  (f32 + bf16 out)
    gemm_small_kernel<<<dim3(NTOK/16, 96/16), 64, 0, stream>>>(
        u_bf, HALF, w_xp, HALF, 96, x_dbl, xdbl_bf);

    // dt_proj: delta = softplus(dt @ W^T + b)
    gemm128_kernel<1,64,1><<<dim3(NTOK/128, HALF/64), 256, 0, stream>>>(
        xdbl_bf, 96, w_dt, DTRANK, HALF, dt_proj_b, nullptr, delta, nullptr, nullptr);

    // chunk-parallel scan (thread per chain, n in registers)
    scan_p1_kernel<<<(BSZ*NCH*HALF)/256, 256, 0, stream>>>(
        delta, u_bf, x_dbl, A_log, hfin, dsum);
    scan_p2_kernel<<<(BSZ*HALF*DSTATE)/256, 256, 0, stream>>>(
        A_log, dsum, hfin, hin);
    scan_p3_kernel<<<(BSZ*NCH*HALF)/256, 256, 0, stream>>>(
        delta, u_bf, x_dbl, A_log, Dp, hin, ycat);

    // out_proj split-K=2: P = ycat @ W^T ; x2 = P0+P1+x
    gemm128_kernel<0,64,2><<<dim3(NTOK/128, DIMD/64, 2), 256, 0, stream>>>(
        ycat, DINNER, w_out, DINNER, DIMD, nullptr, nullptr, P0, P1, nullptr);
    reduce2_kernel<3><<<(NTOK*DIMD)/1024, 256, 0, stream>>>(
        P0, P1, nullptr, x, x2);

    // LN2
    ln_bf16_kernel<<<NTOK, 256, 0, stream>>>(x2, ln2_g, ln2_b, ln2_bf);

    // MLP1: gelu(ln2 @ W1^T + b1) -> bf16 (overwrites scan scratch - ok)
    gemm128_kernel<2,128,1><<<dim3(NTOK/128, MLPD/128), 256, 0, stream>>>(
        ln2_bf, DIMD, w_m1, DIMD, MLPD, mlp_b1, nullptr, nullptr, nullptr, mlp_h);

    // MLP2 split-K=2: P = mlp_h @ W2^T ; out = P0+P1+b2+x2
    gemm128_kernel<0,64,2><<<dim3(NTOK/128, DIMD/64, 2), 256, 0, stream>>>(
        mlp_h, MLPD, w_m2, MLPD, DIMD, nullptr, nullptr, P0, P1, nullptr);
    reduce2_kernel<4><<<(NTOK*DIMD)/1024, 256, 0, stream>>>(
        P0, P1, mlp_b2, x2, out);
}

// Round 7
// 443.922 us; speedup vs baseline: 5.1317x; 1.0834x over previous
//
#include <hip/hip_runtime.h>
#include <math.h>

#define DIMD    1024
#define MLPD    4096
#define DSTATE  16
#define DCONV   4
#define HALF    1024
#define DINNER  2048
#define DTRANK  64
#define BSZ     2
#define SEQ     2048
#define NTOK    (BSZ*SEQ)   // 4096
#define NCH     64
#define CL      (SEQ/NCH)   // 32

typedef short bf16x8 __attribute__((ext_vector_type(8)));
typedef float f32x4  __attribute__((ext_vector_type(4)));
typedef unsigned short u16;
typedef unsigned int   u32;

__device__ __forceinline__ u16 f2bf(float x) {
    union { float f; unsigned int u; } v; v.f = x;
    unsigned int r = (v.u + 0x7FFFu + ((v.u >> 16) & 1u)) >> 16;
    return (u16)r;
}
__device__ __forceinline__ float bf2f(u16 x) {
    union { unsigned int u; float f; } v; v.u = ((unsigned int)x) << 16;
    return v.f;
}

// ---------------- fused LN1 + weight f32->bf16 convert -------------------
#define SZ_WIN  (DINNER*DIMD)
#define SZ_WXP  (96*HALF)
#define SZ_WDT  (HALF*DTRANK)
#define SZ_WOUT (DIMD*DINNER)
#define SZ_WM1  (MLPD*DIMD)
#define SZ_WM2  (DIMD*MLPD)
#define SZ_TOT  (SZ_WIN+SZ_WXP+SZ_WDT+SZ_WOUT+SZ_WM1+SZ_WM2)
#define CVT_BLOCKS ((SZ_TOT + 255) / 256)

__global__ __launch_bounds__(256) void cvtln_kernel(
        const float* __restrict__ x, const float* __restrict__ g,
        const float* __restrict__ b, u16* __restrict__ xn_bf,
        const float* __restrict__ s0, u16* __restrict__ d0,
        const float* __restrict__ s1, u16* __restrict__ d1,
        const float* __restrict__ s2, u16* __restrict__ d2,
        const float* __restrict__ s3, u16* __restrict__ d3,
        const float* __restrict__ s4, u16* __restrict__ d4,
        const float* __restrict__ s5, u16* __restrict__ d5) {
    if (blockIdx.x >= NTOK) {
        int i = (blockIdx.x - NTOK) * 256 + threadIdx.x;
        if (i < SZ_WIN)  { d0[i] = f2bf(s0[i]); return; }  i -= SZ_WIN;
        if (i < SZ_WXP)  { d1[i] = f2bf(s1[i]); return; }  i -= SZ_WXP;
        if (i < SZ_WDT)  { d2[i] = f2bf(s2[i]); return; }  i -= SZ_WDT;
        if (i < SZ_WOUT) { d3[i] = f2bf(s3[i]); return; }  i -= SZ_WOUT;
        if (i < SZ_WM1)  { d4[i] = f2bf(s4[i]); return; }  i -= SZ_WM1;
        if (i < SZ_WM2)  { d5[i] = f2bf(s5[i]); }
        return;
    }
    __shared__ float sm[4];
    int row = blockIdx.x;
    int t = threadIdx.x;
    const float4* xr = (const float4*)(x + (size_t)row * DIMD);
    float4 v = xr[t];
    float s = v.x + v.y + v.z + v.w;
    for (int off = 32; off > 0; off >>= 1) s += __shfl_down(s, off, 64);
    if ((t & 63) == 0) sm[t >> 6] = s;
    __syncthreads();
    float mu = (sm[0] + sm[1] + sm[2] + sm[3]) * (1.0f / DIMD);
    float dx = v.x - mu, dy = v.y - mu, dz = v.z - mu, dw = v.w - mu;
    float ss = dx*dx + dy*dy + dz*dz + dw*dw;
    for (int off = 32; off > 0; off >>= 1) ss += __shfl_down(ss, off, 64);
    __syncthreads();
    if ((t & 63) == 0) sm[t >> 6] = ss;
    __syncthreads();
    float var = (sm[0] + sm[1] + sm[2] + sm[3]) * (1.0f / DIMD);
    float rs = rsqrtf(var + 1e-5f);
    float4 gv = ((const float4*)g)[t];
    float4 bv = ((const float4*)b)[t];
    u16* o = xn_bf + (size_t)row * DIMD + t * 4;
    o[0] = f2bf(dx * rs * gv.x + bv.x);
    o[1] = f2bf(dy * rs * gv.y + bv.y);
    o[2] = f2bf(dz * rs * gv.z + bv.z);
    o[3] = f2bf(dw * rs * gv.w + bv.w);
}

// ---------------- x_proj GEMM: 4 waves = 2 m-tiles x 2 K-halves ----------
__global__ __launch_bounds__(256) void gemm_small_kernel(
        const u16* __restrict__ A, int lda,
        const u16* __restrict__ W, int K, int N,
        float* __restrict__ Cf, u16* __restrict__ Cb) {
    __shared__ f32x4 red[2][64];
    int t = threadIdx.x;
    int w = t >> 6, lane = t & 63;
    int mt = w & 1, kh = w >> 1;
    int m0 = blockIdx.x * 32 + mt * 16;
    int n0 = blockIdx.y * 16;
    int r = lane & 15, quad = lane >> 4;
    int Kh = K >> 1;
    f32x4 acc = {0.f, 0.f, 0.f, 0.f};
    const u16* ap = A + (size_t)(m0 + r) * lda + kh * Kh + quad * 8;
    const u16* wp = W + (size_t)(n0 + r) * K   + kh * Kh + quad * 8;
    for (int k = 0; k < Kh; k += 32) {
        bf16x8 av = *(const bf16x8*)(ap + k);
        bf16x8 bv = *(const bf16x8*)(wp + k);
        acc = __builtin_amdgcn_mfma_f32_16x16x32_bf16(av, bv, acc, 0, 0, 0);
    }
    if (kh == 1) red[mt][lane] = acc;
    __syncthreads();
    if (kh == 0) {
        f32x4 o = red[mt][lane];
        int col = n0 + r;
        #pragma unroll
        for (int i = 0; i < 4; ++i) {
            int row = m0 + quad * 4 + i;
            size_t idx = (size_t)row * N + col;
            float v = acc[i] + o[i];
            Cf[idx] = v;
            Cb[idx] = f2bf(v);
        }
    }
}

// ---------------- big GEMM: 128xTN tile, BK=32, dbuf, hoisted addrs ------
// EPI: 0 f32 | 1 bias+softplus f32 | 2 bias+gelu(tanh) bf16 | 3 +resid f32
//      4 bias+resid f32 | 5 plain bf16
template<int EPI, int TN, int KS>
__global__ __launch_bounds__(256) void gemm128_kernel(
        const u16* __restrict__ A, int lda, const u16* __restrict__ W,
        int K, int N,
        const float* __restrict__ bias, const float* __restrict__ resid,
        float* __restrict__ Cf, float* __restrict__ Cf2,
        u16* __restrict__ Cb) {
    constexpr int NF = TN / 32;
    __shared__ u16 As0[128 * 32], As1[128 * 32];
    __shared__ u16 Bs0[TN * 32],  Bs1[TN * 32];
    const int t = threadIdx.x;
    const int w = t >> 6;
    const int lane = t & 63;
    const int r = lane & 15, quad = lane >> 4;
    const int wm = w & 1, wn = w >> 1;
    const int m0 = blockIdx.x * 128;
    const int n0 = blockIdx.y * TN;
    const int Kloc = K / KS;
    const int kz = (KS == 2) ? blockIdx.z : 0;

    f32x4 acc[4][NF];
    #pragma unroll
    for (int mi = 0; mi < 4; ++mi)
        #pragma unroll
        for (int ni = 0; ni < NF; ++ni)
            acc[mi][ni] = (f32x4){0.f, 0.f, 0.f, 0.f};

    const u16* pa[2];
    const u16* pb[NF / 2];
    #pragma unroll
    for (int i = 0; i < 2; ++i) {
        int c = (i * 4 + w) * 64 + lane;
        int row = c >> 2;
        int q = (c & 3) ^ ((row >> 1) & 3);
        pa[i] = A + (size_t)(m0 + row) * lda + (size_t)kz * Kloc + q * 8;
    }
    #pragma unroll
    for (int i = 0; i < NF / 2; ++i) {
        int c = (i * 4 + w) * 64 + lane;
        int row = c >> 2;
        int q = (c & 3) ^ ((row >> 1) & 3);
        pb[i] = W + (size_t)(n0 + row) * K + (size_t)kz * Kloc + q * 8;
    }
    const int qs = quad ^ ((r >> 1) & 3);
    int aoff[4], boff[NF];
    #pragma unroll
    for (int mi = 0; mi < 4; ++mi)
        aoff[mi] = (wm * 64 + mi * 16 + r) * 32 + qs * 8;
    #pragma unroll
    for (int ni = 0; ni < NF; ++ni)
        boff[ni] = (wn * (TN / 2) + ni * 16 + r) * 32 + qs * 8;

    auto stage = [&](u16* __restrict__ Ad, u16* __restrict__ Bd) {
        #pragma unroll
        for (int i = 0; i < 2; ++i) {
            __builtin_amdgcn_global_load_lds(
                (const __attribute__((address_space(1))) u32*)pa[i],
                (__attribute__((address_space(3))) u32*)(Ad + (i * 4 + w) * 512),
                16, 0, 0);
            pa[i] += 32;
        }
        #pragma unroll
        for (int i = 0; i < NF / 2; ++i) {
            __builtin_amdgcn_global_load_lds(
                (const __attribute__((address_space(1))) u32*)pb[i],
                (__attribute__((address_space(3))) u32*)(Bd + (i * 4 + w) * 512),
                16, 0, 0);
            pb[i] += 32;
        }
    };
    auto compute = [&](const u16* __restrict__ Ab, const u16* __restrict__ Bb) {
        bf16x8 af[4], bfr[NF];
        #pragma unroll
        for (int mi = 0; mi < 4; ++mi) af[mi] = *(const bf16x8*)(Ab + aoff[mi]);
        #pragma unroll
        for (int ni = 0; ni < NF; ++ni) bfr[ni] = *(const bf16x8*)(Bb + boff[ni]);
        #pragma unroll
        for (int mi = 0; mi < 4; ++mi)
            #pragma unroll
            for (int ni = 0; ni < NF; ++ni)
                acc[mi][ni] = __builtin_amdgcn_mfma_f32_16x16x32_bf16(
                    af[mi], bfr[ni], acc[mi][ni], 0, 0, 0);
    };

    stage(As0, Bs0);
    for (int k0 = 0; k0 < Kloc; k0 += 64) {
        __syncthreads();
        if (k0 + 32 < Kloc) stage(As1, Bs1);
        compute(As0, Bs0);
        __syncthreads();
        if (k0 + 64 < Kloc) stage(As0, Bs0);
        compute(As1, Bs1);
    }

    float* Cfo = (KS == 2 && kz) ? Cf2 : Cf;
    #pragma unroll
    for (int mi = 0; mi < 4; ++mi) {
        #pragma unroll
        for (int i = 0; i < 4; ++i) {
            int row = m0 + wm * 64 + mi * 16 + quad * 4 + i;
            #pragma unroll
            for (int ni = 0; ni < NF; ++ni) {
                int col = n0 + wn * (TN / 2) + ni * 16 + r;
                size_t idx = (size_t)row * N + col;
                float v = acc[mi][ni][i];
                if (EPI == 1) { v += bias[col]; v = (v > 20.f) ? v : log1pf(expf(v)); }
                if (EPI == 2) {
                    v += bias[col];
                    // gelu, tanh form: v * e/(e+1), e = exp(2*0.7978845608*(v+0.044715 v^3))
                    float e = __expf(fminf(1.5957691216f * v + 0.0713548162f * v * v * v, 80.f));
                    v = v * __fdividef(e, e + 1.f);
                }
                if (EPI == 3) { v += resid[idx]; }
                if (EPI == 4) { v += bias[col] + resid[idx]; }
                if (EPI == 2 || EPI == 5) Cb[idx] = f2bf(v);
                else                      Cfo[idx] = v;
            }
        }
    }
}

// ---------------- split-K reduce: out = P0 + P1 + bias + resid -----------
__global__ __launch_bounds__(256) void reduce2_kernel(
        const float* __restrict__ P0, const float* __restrict__ P1,
        const float* __restrict__ bias, const float* __restrict__ resid,
        float* __restrict__ out) {
    size_t idx = ((size_t)blockIdx.x * 256 + threadIdx.x) * 4;
    float4 a = *(const float4*)(P0 + idx);
    float4 b = *(const float4*)(P1 + idx);
    float4 rr = *(const float4*)(resid + idx);
    int col = (int)(idx & (DIMD - 1));
    float4 bb = *(const float4*)(bias + col);
    float4 o;
    o.x = a.x + b.x + rr.x + bb.x;
    o.y = a.y + b.y + rr.y + bb.y;
    o.z = a.z + b.z + rr.z + bb.z;
    o.w = a.w + b.w + rr.w + bb.w;
    *(float4*)(out + idx) = o;
}

// ---------------- fused out_proj reduce + residual + LN2 -----------------
// x2 = P0 + P1 + resid ; ln2_bf = LN(x2)*g + b   (block per row)
__global__ __launch_bounds__(256) void reduce_ln_kernel(
        const float* __restrict__ P0, const float* __restrict__ P1,
        const float* __restrict__ resid,
        const float* __restrict__ g, const float* __restrict__ b,
        float* __restrict__ x2, u16* __restrict__ out_bf) {
    __shared__ float sm[4];
    int row = blockIdx.x;
    int t = threadIdx.x;
    size_t base = (size_t)row * DIMD + t * 4;
    float4 a  = *(const float4*)(P0 + base);
    float4 p  = *(const float4*)(P1 + base);
    float4 rr = *(const float4*)(resid + base);
    float4 v;
    v.x = a.x + p.x + rr.x;
    v.y = a.y + p.y + rr.y;
    v.z = a.z + p.z + rr.z;
    v.w = a.w + p.w + rr.w;
    *(float4*)(x2 + base) = v;
    float s = v.x + v.y + v.z + v.w;
    for (int off = 32; off > 0; off >>= 1) s += __shfl_down(s, off, 64);
    if ((t & 63) == 0) sm[t >> 6] = s;
    __syncthreads();
    float mu = (sm[0] + sm[1] + sm[2] + sm[3]) * (1.0f / DIMD);
    float dx = v.x - mu, dy = v.y - mu, dz = v.z - mu, dw = v.w - mu;
    float ss = dx*dx + dy*dy + dz*dz + dw*dw;
    for (int off = 32; off > 0; off >>= 1) ss += __shfl_down(ss, off, 64);
    __syncthreads();
    if ((t & 63) == 0) sm[t >> 6] = ss;
    __syncthreads();
    float var = (sm[0] + sm[1] + sm[2] + sm[3]) * (1.0f / DIMD);
    float rs = rsqrtf(var + 1e-5f);
    float4 gv = ((const float4*)g)[t];
    float4 bv = ((const float4*)b)[t];
    u16* o = out_bf + base;
    o[0] = f2bf(dx * rs * gv.x + bv.x);
    o[1] = f2bf(dy * rs * gv.y + bv.y);
    o[2] = f2bf(dz * rs * gv.z + bv.z);
    o[3] = f2bf(dw * rs * gv.w + bv.w);
}

// ---------------- depthwise conv + SiLU, sliding window (8 l / thread) ---
__global__ __launch_bounds__(256) void conv_silu_kernel(
        const u16* __restrict__ xz,
        const float* __restrict__ wx, const float* __restrict__ bx,
        const float* __restrict__ wz, const float* __restrict__ bz,
        u16* __restrict__ u_bf, u16* __restrict__ ycat) {
    int c  = blockIdx.x * 256 + threadIdx.x;   // 0..1023
    int gy = blockIdx.y;                       // 0..NTOK/8-1
    int b  = gy >> 8;                          // SEQ/8 = 256 chunks per batch
    int l0 = (gy & 255) * 8;
    const u16* base = xz + ((size_t)(b * SEQ + l0)) * DINNER;
    float wxr[4], wzr[4];
    #pragma unroll
    for (int k = 0; k < 4; ++k) { wxr[k] = wx[c * 4 + k]; wzr[k] = wz[c * 4 + k]; }
    float bxv = bx[c], bzv = bz[c];
    // window: rows l-1, l, l+1 (x and z halves)
    float xm1 = (l0 > 0) ? bf2f(base[c - DINNER]) : 0.f;
    float x0v = bf2f(base[c]);
    float x1v = bf2f(base[c + DINNER]);
    float zm1 = (l0 > 0) ? bf2f(base[HALF + c - DINNER]) : 0.f;
    float z0v = bf2f(base[HALF + c]);
    float z1v = bf2f(base[HALF + c + DINNER]);
    u16* up = u_bf + ((size_t)(b * SEQ + l0)) * HALF + c;
    u16* yp = ycat + ((size_t)(b * SEQ + l0)) * DINNER + HALF + c;
    #pragma unroll
    for (int l = 0; l < 8; ++l) {
        bool in = (l0 + l + 2) < SEQ;
        float x2v = in ? bf2f(base[(size_t)(l + 2) * DINNER + c]) : 0.f;
        float z2v = in ? bf2f(base[(size_t)(l + 2) * DINNER + HALF + c]) : 0.f;
        float ax = bxv + wxr[0]*xm1 + wxr[1]*x0v + wxr[2]*x1v + wxr[3]*x2v;
        float az = bzv + wzr[0]*zm1 + wzr[1]*z0v + wzr[2]*z1v + wzr[3]*z2v;
        float sx = ax * __fdividef(1.f, 1.f + __expf(-ax));
        float sz = az * __fdividef(1.f, 1.f + __expf(-az));
        *up = f2bf(sx); *yp = f2bf(sz);
        up += HALF; yp += DINNER;
        xm1 = x0v; x0v = x1v; x1v = x2v;
        zm1 = z0v; z0v = z1v; z1v = z2v;
    }
}

// ---------------- chunk-parallel selective scan (thread per chain) -------
__global__ __launch_bounds__(256) void scan_p1_kernel(
        const float* __restrict__ delta, const u16* __restrict__ u_bf,
        const float* __restrict__ x_dbl, const float* __restrict__ A_log,
        float* __restrict__ hfin, float* __restrict__ dsum) {
    int t  = blockIdx.x * 256 + threadIdx.x;
    int d  = t & (HALF - 1);
    int ch = (t >> 10) & (NCH - 1);
    int b  = t >> 16;
    float Ac[16], h[16];
    #pragma unroll
    for (int i = 0; i < 4; ++i) {
        float4 a = *(const float4*)&A_log[d * DSTATE + i * 4];
        Ac[4*i+0] = -__expf(a.x); Ac[4*i+1] = -__expf(a.y);
        Ac[4*i+2] = -__expf(a.z); Ac[4*i+3] = -__expf(a.w);
        h[4*i+0] = 0.f; h[4*i+1] = 0.f; h[4*i+2] = 0.f; h[4*i+3] = 0.f;
    }
    int l0 = b * SEQ + ch * CL;
    size_t off = (size_t)l0 * HALF + d;
    const float* xrow = x_dbl + (size_t)l0 * 96;
    float ds = 0.f;
    #pragma unroll 4
    for (int l = 0; l < CL; ++l) {
        float dl = delta[off];
        float uv = bf2f(u_bf[off]);
        off += HALF;
        float4 B0 = *(const float4*)(xrow + 64);
        float4 B1 = *(const float4*)(xrow + 68);
        float4 B2 = *(const float4*)(xrow + 72);
        float4 B3 = *(const float4*)(xrow + 76);
        xrow += 96;
        float dBu = dl * uv;
        ds += dl;
        float Bv[16] = {B0.x,B0.y,B0.z,B0.w, B1.x,B1.y,B1.z,B1.w,
                        B2.x,B2.y,B2.z,B2.w, B3.x,B3.y,B3.z,B3.w};
        #pragma unroll
        for (int n = 0; n < 16; ++n)
            h[n] = __expf(dl * Ac[n]) * h[n] + dBu * Bv[n];
    }
    float4* hf = (float4*)&hfin[(size_t)t * 16];
    #pragma unroll
    for (int i = 0; i < 4; ++i)
        hf[i] = (float4){h[4*i+0], h[4*i+1], h[4*i+2], h[4*i+3]};
    dsum[t] = ds;
}

__global__ __launch_bounds__(256) void scan_p2_kernel(
        const float* __restrict__ A_log, const float* __restrict__ dsum,
        const float* __restrict__ hfin, float* __restrict__ hin) {
    int t = blockIdx.x * 256 + threadIdx.x;
    int n = t & 15;
    int d = (t >> 4) & (HALF - 1);
    int b = t >> 14;
    float Ac = -__expf(A_log[d * DSTATE + n]);
    float h = 0.f;
    for (int ch = 0; ch < NCH; ++ch) {
        size_t chain = ((size_t)(b * NCH + ch) * HALF) + d;
        hin[chain * 16 + n] = h;
        float ds = dsum[chain];
        h = __expf(Ac * ds) * h + hfin[chain * 16 + n];
    }
}

__global__ __launch_bounds__(256) void scan_p3_kernel(
        const float* __restrict__ delta, const u16* __restrict__ u_bf,
        const float* __restrict__ x_dbl, const float* __restrict__ A_log,
        const float* __restrict__ Dp, const float* __restrict__ hin,
        u16* __restrict__ ycat) {
    int t  = blockIdx.x * 256 + threadIdx.x;
    int d  = t & (HALF - 1);
    int ch = (t >> 10) & (NCH - 1);
    int b  = t >> 16;
    float Ac[16], h[16];
    #pragma unroll
    for (int i = 0; i < 4; ++i) {
        float4 a  = *(const float4*)&A_log[d * DSTATE + i * 4];
        float4 hv = *(const float4*)&hin[(size_t)t * 16 + i * 4];
        Ac[4*i+0] = -__expf(a.x); Ac[4*i+1] = -__expf(a.y);
        Ac[4*i+2] = -__expf(a.z); Ac[4*i+3] = -__expf(a.w);
        h[4*i+0] = hv.x; h[4*i+1] = hv.y; h[4*i+2] = hv.z; h[4*i+3] = hv.w;
    }
    float Dv = Dp[d];
    int l0 = b * SEQ + ch * CL;
    size_t off = (size_t)l0 * HALF + d;
    const float* xrow = x_dbl + (size_t)l0 * 96;
    u16* yp = ycat + (size_t)l0 * DINNER + d;
    #pragma unroll 4
    for (int l = 0; l < CL; ++l) {
        float dl = delta[off];
        float uv = bf2f(u_bf[off]);
        off += HALF;
        float4 B0 = *(const float4*)(xrow + 64);
        float4 B1 = *(const float4*)(xrow + 68);
        float4 B2 = *(const float4*)(xrow + 72);
        float4 B3 = *(const float4*)(xrow + 76);
        float4 C0 = *(const float4*)(xrow + 80);
        float4 C1 = *(const float4*)(xrow + 84);
        float4 C2 = *(const float4*)(xrow + 88);
        float4 C3 = *(const float4*)(xrow + 92);
        xrow += 96;
        float dBu = dl * uv;
        float Bv[16] = {B0.x,B0.y,B0.z,B0.w, B1.x,B1.y,B1.z,B1.w,
                        B2.x,B2.y,B2.z,B2.w, B3.x,B3.y,B3.z,B3.w};
        float Cv[16] = {C0.x,C0.y,C0.z,C0.w, C1.x,C1.y,C1.z,C1.w,
                        C2.x,C2.y,C2.z,C2.w, C3.x,C3.y,C3.z,C3.w};
        float y = uv * Dv;
        #pragma unroll
        for (int n = 0; n < 16; ++n) {
            h[n] = __expf(dl * Ac[n]) * h[n] + dBu * Bv[n];
            y += h[n] * Cv[n];
        }
        *yp = f2bf(y);
        yp += DINNER;
    }
}

// ---------------- host-side orchestration ----------------
extern "C" void kernel_launch(void* const* d_in, const int* in_sizes, int n_in,
                              void* d_out, int out_size, void* d_ws, size_t ws_size,
                              hipStream_t stream) {
    const float* x         = (const float*)d_in[0];
    const float* ln1_g     = (const float*)d_in[1];
    const float* ln1_b     = (const float*)d_in[2];
    const float* in_proj_w = (const float*)d_in[3];
    const float* conv_x_w  = (const float*)d_in[4];
    const float* conv_x_b  = (const float*)d_in[5];
    const float* conv_z_w  = (const float*)d_in[6];
    const float* conv_z_b  = (const float*)d_in[7];
    const float* x_proj_w  = (const float*)d_in[8];
    const float* dt_proj_w = (const float*)d_in[9];
    const float* dt_proj_b = (const float*)d_in[10];
    const float* A_log     = (const float*)d_in[11];
    const float* Dp        = (const float*)d_in[12];
    const float* out_proj_w= (const float*)d_in[13];
    const float* ln2_g     = (const float*)d_in[14];
    const float* ln2_b     = (const float*)d_in[15];
    const float* mlp_w1    = (const float*)d_in[16];
    const float* mlp_b1    = (const float*)d_in[17];
    const float* mlp_w2    = (const float*)d_in[18];
    const float* mlp_b2    = (const float*)d_in[19];
    float* out = (float*)d_out;

    char* p = (char*)d_ws;
    auto alloc = [&](size_t bytes) {
        char* r = p; p += (bytes + 255) & ~(size_t)255; return r;
    };
    u16*   w_in   = (u16*)  alloc((size_t)DINNER * DIMD * 2);
    u16*   w_xp   = (u16*)  alloc((size_t)96 * HALF * 2);
    u16*   w_dt   = (u16*)  alloc((size_t)HALF * DTRANK * 2);
    u16*   w_out  = (u16*)  alloc((size_t)DIMD * DINNER * 2);
    u16*   w_m1   = (u16*)  alloc((size_t)MLPD * DIMD * 2);
    u16*   w_m2   = (u16*)  alloc((size_t)DIMD * MLPD * 2);
    u16*   xn_bf  = (u16*)  alloc((size_t)NTOK * DIMD * 2);
    u16*   xz_bf  = (u16*)  alloc((size_t)NTOK * DINNER * 2);  // 16 MB
    u16*   u_bf   = (u16*)  alloc((size_t)NTOK * HALF * 2);
    u16*   ycat   = (u16*)  alloc((size_t)NTOK * DINNER * 2);
    float* x_dbl  = (float*)alloc((size_t)NTOK * 96 * 4);
    u16*   xdbl_bf= (u16*)  alloc((size_t)NTOK * 96 * 2);
    float* delta  = (float*)alloc((size_t)NTOK * HALF * 4);    // 16 MB
    float* x2     = (float*)alloc((size_t)NTOK * DIMD * 4);
    u16*   ln2_bf = (u16*)  alloc((size_t)NTOK * DIMD * 2);
    u16*   mlp_h  = (u16*)  alloc((size_t)NTOK * MLPD * 2);    // 32 MB
    // scan scratch aliases mlp_h (dead until mlp1):
    float* hfin = (float*)mlp_h;
    float* hin  = hfin + (size_t)BSZ * NCH * HALF * DSTATE;
    float* dsum = hin  + (size_t)BSZ * NCH * HALF * DSTATE;
    // split-K partials alias delta (dead after scan) and xz_bf (dead after conv):
    float* P0 = delta;
    float* P1 = (float*)xz_bf;

    // fused LN1 + weight conversions
    cvtln_kernel<<<NTOK + CVT_BLOCKS, 256, 0, stream>>>(
        x, ln1_g, ln1_b, xn_bf,
        in_proj_w, w_in, x_proj_w, w_xp, dt_proj_w, w_dt,
        out_proj_w, w_out, mlp_w1, w_m1, mlp_w2, w_m2);

    // in_proj: xz_bf[4096,2048] = xn @ W^T (bf16 out, TN=64 -> 1024 blocks)
    gemm128_kernel<5,64,1><<<dim3(NTOK/128, DINNER/64), 256, 0, stream>>>(
        xn_bf, DIMD, w_in, DIMD, DINNER, nullptr, nullptr, nullptr, nullptr, xz_bf);

    // depthwise conv + silu (sliding window)
    conv_silu_kernel<<<dim3(HALF/256, NTOK/8), 256, 0, stream>>>(
        xz_bf, conv_x_w, conv_x_b, conv_z_w, conv_z_b, u_bf, ycat);

    // x_proj: [4096,96] = u @ W^T  (split-K in block)
    gemm_small_kernel<<<dim3(NTOK/32, 96/16), 256, 0, stream>>>(
        u_bf, HALF, w_xp, HALF, 96, x_dbl, xdbl_bf);

    // dt_proj: delta = softplus(dt @ W^T + b)
    gemm128_kernel<1,64,1><<<dim3(NTOK/128, HALF/64), 256, 0, stream>>>(
        xdbl_bf, 96, w_dt, DTRANK, HALF, dt_proj_b, nullptr, delta, nullptr, nullptr);

    // chunk-parallel scan
    scan_p1_kernel<<<(BSZ*NCH*HALF)/256, 256, 0, stream>>>(
        delta, u_bf, x_dbl, A_log, hfin, dsum);
    scan_p2_kernel<<<(BSZ*HALF*DSTATE)/256, 256, 0, stream>>>(
        A_log, dsum, hfin, hin);
    scan_p3_kernel<<<(BSZ*NCH*HALF)/256, 256, 0, stream>>>(
        delta, u_bf, x_dbl, A_log, Dp, hin, ycat);

    // out_proj split-K=2: P = ycat @ W^T
    gemm128_kernel<0,64,2><<<dim3(NTOK/128, DIMD/64, 2), 256, 0, stream>>>(
        ycat, DINNER, w_out, DINNER, DIMD, nullptr, nullptr, P0, P1, nullptr);
    // fused: x2 = P0+P1+x ; ln2_bf = LN(x2)
    reduce_ln_kernel<<<NTOK, 256, 0, stream>>>(
        P0, P1, x, ln2_g, ln2_b, x2, ln2_bf);

    // MLP1: gelu(ln2 @ W1^T + b1) -> bf16 (overwrites scan scratch - ok)
    gemm128_kernel<2,128,1><<<dim3(NTOK/128, MLPD/128), 256, 0, stream>>>(
        ln2_bf, DIMD, w_m1, DIMD, MLPD, mlp_b1, nullptr, nullptr, nullptr, mlp_h);

    // MLP2 split-K=2: P = mlp_h @ W2^T ; out = P0+P1+b2+x2
    gemm128_kernel<0,64,2><<<dim3(NTOK/128, DIMD/64, 2), 256, 0, stream>>>(
        mlp_h, MLPD, w_m2, MLPD, DIMD, nullptr, nullptr, P0, P1, nullptr);
    reduce2_kernel<<<(NTOK*DIMD)/1024, 256, 0, stream>>>(
        P0, P1, mlp_b2, x2, out);
}